// Round 3
// baseline (3296.445 us; speedup 1.0000x reference)
//
#include <hip/hip_runtime.h>
#include <cstdint>
#include <cstddef>

// ---------------------------------------------------------------------------
// GCN 2-layer forward — linear-network restructure:
//   out = Â·(Â·(X·W12)) + p·c2ᵀ + 1·b2ᵀ,  W12 = W1·W2, c2 = W2ᵀ·b1, p = Â·1
// where Â = D^{-1/2}(A+I)D^{-1/2}. Aggregation uses 196 dst-buckets of
// (src,dst) records built with full-cacheline chunk flushes (no partial-line
// write amplification), consumed by LDS-accumulator blocks (no global float
// atomics).
// ---------------------------------------------------------------------------

#define NB    196     // buckets: dst >> 9, 512 nodes each (N = 100000)
#define BSH   9
#define CAPR  20000   // per-bucket record capacity (mean 16327, sigma ~127)
#define CAPS  40      // LDS staging rows per bucket
#define PBLK  128     // partition blocks

// Partition edges into dst-buckets; also counts in-degree.
// Staged in LDS; flushed in full 16-record (128 B) chunks by a single thread
// per bucket so every cache line has exactly one writer.
__global__ __launch_bounds__(256) void partition_k(
    const int* __restrict__ src, const int* __restrict__ dst,
    int* __restrict__ deg, int* __restrict__ gcur, uint2* __restrict__ recs,
    int E) {
    __shared__ uint2 stag[NB][CAPS];
    __shared__ int scnt[NB];
    const int t = threadIdx.x;
    for (int i = t; i < NB; i += 256) scnt[i] = 0;
    __syncthreads();

    const int per = (E + PBLK - 1) / PBLK;
    const int beg = blockIdx.x * per;
    const int end = min(beg + per, E);

    for (int ph = beg; ph < end; ph += 1024) {
        const int lim = min(ph + 1024, end);
        for (int e = ph + t; e < lim; e += 256) {
            const int d = dst[e], s = src[e];
            atomicAdd(&deg[d], 1);
            const int b = d >> BSH;
            const int slot = atomicAdd(&scnt[b], 1);
            if (slot < CAPS) {
                stag[b][slot] = make_uint2((unsigned)s, (unsigned)d);
            } else {  // statistically ~never: direct global fallback
                const int p = atomicAdd(&gcur[b], 1);
                recs[(size_t)b * CAPR + p] = make_uint2((unsigned)s, (unsigned)d);
            }
        }
        __syncthreads();
        if (t < NB) {
            const int c = min(scnt[t], CAPS);
            const int nch = c >> 4;
            if (nch) {
                const int p = atomicAdd(&gcur[t], nch << 4);
                uint2* dp = recs + (size_t)t * CAPR + p;
                for (int j = 0; j < (nch << 4); ++j) dp[j] = stag[t][j];
                const int rem = c & 15;
                for (int j = 0; j < rem; ++j) stag[t][j] = stag[t][(nch << 4) + j];
                scnt[t] = rem;
            } else {
                scnt[t] = c;
            }
        }
        __syncthreads();
    }
    if (t < NB) {  // tail (partial chunk, once per block per bucket)
        const int c = scnt[t];
        if (c) {
            const int p = atomicAdd(&gcur[t], c);
            uint2* dp = recs + (size_t)t * CAPR + p;
            for (int j = 0; j < c; ++j) dp[j] = stag[t][j];
        }
    }
}

__global__ __launch_bounds__(256) void dinv_k(const int* __restrict__ deg,
                                              float* __restrict__ dinv, int N) {
    int i = blockIdx.x * 256 + threadIdx.x;
    if (i < N) dinv[i] = rsqrtf((float)(deg[i] + 1));  // +1 = self loop
}

// W12 = W1 [128x128] @ W2 [128x64]; c2 = W2^T b1 [64]
__global__ __launch_bounds__(256) void w12_k(
    const float* __restrict__ W1, const float* __restrict__ W2,
    const float* __restrict__ b1, float* __restrict__ W12, float* __restrict__ c2) {
    const int t = threadIdx.x;
    if (blockIdx.x < 32) {
        const int r = blockIdx.x * 4 + (t >> 6);
        const int c = t & 63;
        float acc = 0.f;
        for (int k = 0; k < 128; ++k) acc += W1[r * 128 + k] * W2[k * 64 + c];
        W12[r * 64 + c] = acc;
    } else if (t < 64) {
        float acc = 0.f;
        for (int k = 0; k < 128; ++k) acc += b1[k] * W2[k * 64 + t];
        c2[t] = acc;
    }
}

// g = dinv * (X [N,128] @ W [128,64]); 16 rows x 64 cols per block.
__global__ __launch_bounds__(256) void gemm_scale_k(
    const float* __restrict__ X, const float* __restrict__ W,
    const float* __restrict__ dinv, float* __restrict__ g, int N) {
    __shared__ float Ws[64 * 64];
    __shared__ float Xs[16 * 128];

    const int t = threadIdx.x;
    const int row0 = blockIdx.x * 16;

    for (int i = t; i < 16 * 128; i += 256) {
        int r = i >> 7, k = i & 127;
        int gr = row0 + r;
        Xs[i] = (gr < N) ? X[(size_t)gr * 128 + k] : 0.0f;
    }

    const int c  = t & 63;
    const int rg = t >> 6;

    float acc[4] = {0.f, 0.f, 0.f, 0.f};

    for (int kc = 0; kc < 2; ++kc) {
        for (int i = t; i < 64 * 64; i += 256) Ws[i] = W[kc * 64 * 64 + i];
        __syncthreads();
#pragma unroll 4
        for (int kk = 0; kk < 64; ++kk) {
            const int k = kc * 64 + kk;
            const float w = Ws[kk * 64 + c];
#pragma unroll
            for (int i = 0; i < 4; ++i)
                acc[i] += Xs[(rg * 4 + i) * 128 + k] * w;
        }
        __syncthreads();
    }

#pragma unroll
    for (int i = 0; i < 4; ++i) {
        int gr = row0 + rg * 4 + i;
        if (gr < N) g[(size_t)gr * 64 + c] = acc[i] * dinv[gr];
    }
}

// One block per (bucket, quarter): LDS-accumulate neighbor sums for 128 nodes.
// PASS2=0: outp[d] = dinv[d]^2*(gin[d]+sum) (pre-scaled for next hop); also
//          p[d] = dinv[d]*(dinv[d] + sum dinv[s]).
// PASS2=1: outp[d] = dinv[d]*(gin[d]+sum) + p[d]*c2[c] + b2[c].
template <int PASS2>
__global__ __launch_bounds__(256) void agg_k(
    const float* __restrict__ gin, const uint2* __restrict__ recs,
    const int* __restrict__ bcnt, const float* __restrict__ dinv,
    float* __restrict__ outp, float* __restrict__ p,
    const float* __restrict__ c2, const float* __restrict__ b2, int N) {
    __shared__ float sacc[128 * 64];
    __shared__ float spacc[128];
    const int t = threadIdx.x;
    const int bucket = blockIdx.x >> 2, sub = blockIdx.x & 3;
    const int node0 = (bucket << 9) + (sub << 7);

    for (int i = t; i < 128 * 64; i += 256) sacc[i] = 0.f;
    if (t < 128) spacc[t] = 0.f;
    __syncthreads();

    const size_t base = (size_t)bucket * CAPR;
    const int cnt = bcnt[bucket];
    const int w = t >> 6, lane = t & 63;
    const int g16 = lane >> 4;            // record slot within group-of-4
    const int fq  = (lane & 15) << 2;     // feature quad

    for (int r0 = w * 4 + g16; r0 < cnt; r0 += 16) {
        const uint2 rec = recs[base + r0];
        const unsigned dl = rec.y - (unsigned)node0;
        if (dl < 128u) {
            const float4 v = *(const float4*)(gin + (size_t)rec.x * 64 + fq);
            atomicAdd(&sacc[(dl << 6) + fq + 0], v.x);
            atomicAdd(&sacc[(dl << 6) + fq + 1], v.y);
            atomicAdd(&sacc[(dl << 6) + fq + 2], v.z);
            atomicAdd(&sacc[(dl << 6) + fq + 3], v.w);
            if (!PASS2 && (lane & 15) == 0) atomicAdd(&spacc[dl], dinv[rec.x]);
        }
    }
    __syncthreads();

    for (int idx = t; idx < 128 * 64; idx += 256) {
        const int dl = idx >> 6, c = idx & 63;
        const int d = node0 + dl;
        if (d < N) {
            const float di = dinv[d];
            float v = (gin[(size_t)d * 64 + c] + sacc[idx]);
            if (PASS2)
                v = v * di + p[d] * c2[c] + b2[c];
            else
                v = v * di * di;   // pre-scale by dinv for the next hop
            outp[(size_t)d * 64 + c] = v;
        }
    }
    if (!PASS2 && t < 128) {
        const int d = node0 + t;
        if (d < N) p[d] = dinv[d] * (dinv[d] + spacc[t]);
    }
}

extern "C" void kernel_launch(void* const* d_in, const int* in_sizes, int n_in,
                              void* d_out, int out_size, void* d_ws, size_t ws_size,
                              hipStream_t stream) {
    const float* x  = (const float*)d_in[0];
    const int*   ei = (const int*)d_in[1];
    const float* W1 = (const float*)d_in[2];
    const float* b1 = (const float*)d_in[3];
    const float* W2 = (const float*)d_in[4];
    const float* b2 = (const float*)d_in[5];
    float* out = (float*)d_out;

    const int N = in_sizes[0] / 128;   // 100000
    const int E = in_sizes[1] / 2;     // 3200000
    const int* src = ei;
    const int* dst = ei + E;

    char* ws = (char*)d_ws;
    auto take = [&](size_t bytes) { char* q = ws; ws += (bytes + 255) & ~(size_t)255; return q; };
    int*   deg  = (int*)  take((size_t)N * 4);
    float* dinv = (float*)take((size_t)N * 4);
    float* pbuf = (float*)take((size_t)N * 4);
    int*   gcur = (int*)  take(NB * 4);
    float* W12  = (float*)take(128 * 64 * 4);
    float* c2   = (float*)take(64 * 4);
    uint2* recs = (uint2*)take((size_t)NB * CAPR * 8);
    float* g    = (float*)take((size_t)N * 64 * 4);
    float* t1   = (float*)take((size_t)N * 64 * 4);

    hipMemsetAsync(deg, 0, (size_t)N * 4, stream);
    hipMemsetAsync(gcur, 0, NB * 4, stream);

    partition_k<<<PBLK, 256, 0, stream>>>(src, dst, deg, gcur, recs, E);
    dinv_k<<<(N + 255) / 256, 256, 0, stream>>>(deg, dinv, N);
    w12_k<<<33, 256, 0, stream>>>(W1, W2, b1, W12, c2);

    gemm_scale_k<<<(N + 15) / 16, 256, 0, stream>>>(x, W12, dinv, g, N);
    agg_k<0><<<NB * 4, 256, 0, stream>>>(g,  recs, gcur, dinv, t1,  pbuf, c2, b2, N);
    agg_k<1><<<NB * 4, 256, 0, stream>>>(t1, recs, gcur, dinv, out, pbuf, c2, b2, N);
}

// Round 4
// 586.119 us; speedup vs baseline: 5.6242x; 5.6242x over previous
//
#include <hip/hip_runtime.h>
#include <cstdint>
#include <cstddef>

// ---------------------------------------------------------------------------
// GCN 2-layer forward — linear-network restructure (validated round 3):
//   out = Â·(Â·(X·W12)) + p·c2ᵀ + 1·b2ᵀ,  W12 = W1·W2, c2 = W2ᵀ·b1, p = Â·1
// CSR built via 2-phase bucket counting-sort (full-cacheline writes only),
// aggregation via wave-per-node register-accumulator gather (no atomics).
// ---------------------------------------------------------------------------

#define NB    391     // buckets of 256 dst nodes (N = 100000 -> 391)
#define BSH   8
#define CAPR  9216    // per-bucket record cap (mean 8184, sigma ~90; >11 sigma)
#define CAPS  32      // LDS staging slots per bucket (flush chunk = 32 recs = 128B)
#define PBLK  128

// records: (dst & 255) << 17 | src   (src < 2^17)

__global__ __launch_bounds__(256) void partition_k(
    const int* __restrict__ src, const int* __restrict__ dst,
    int* __restrict__ gcur, unsigned* __restrict__ recs, int E) {
    __shared__ unsigned stag[NB][CAPS];
    __shared__ int scnt[NB];
    const int t = threadIdx.x;
    for (int i = t; i < NB; i += 256) scnt[i] = 0;
    __syncthreads();

    const int per = (E + PBLK - 1) / PBLK;
    const int beg = blockIdx.x * per;
    const int end = min(beg + per, E);

    for (int ph = beg; ph < end; ph += 1024) {
        const int lim = min(ph + 1024, end);
        for (int e = ph + t; e < lim; e += 256) {
            const int d = dst[e], s = src[e];
            const int b = d >> BSH;
            const unsigned rec = ((unsigned)(d & 255) << 17) | (unsigned)s;
            const int slot = atomicAdd(&scnt[b], 1);
            if (slot < CAPS) {
                stag[b][slot] = rec;
            } else {  // statistically ~never
                const int p = atomicAdd(&gcur[b], 1);
                recs[(size_t)b * CAPR + p] = rec;
            }
        }
        __syncthreads();
        for (int b = t; b < NB; b += 256) {
            const int c = min(scnt[b], CAPS);
            const int nch = c >> 5;
            if (nch) {
                const int p = atomicAdd(&gcur[b], nch << 5);
                unsigned* dp = recs + (size_t)b * CAPR + p;
                for (int j = 0; j < (nch << 5); ++j) dp[j] = stag[b][j];
                const int rem = c & 31;
                for (int j = 0; j < rem; ++j) stag[b][j] = stag[b][(nch << 5) + j];
                scnt[b] = rem;
            } else {
                scnt[b] = c;
            }
        }
        __syncthreads();
    }
    for (int b = t; b < NB; b += 256) {
        const int c = scnt[b];
        if (c) {
            const int p = atomicAdd(&gcur[b], c);
            unsigned* dp = recs + (size_t)b * CAPR + p;
            for (int j = 0; j < c; ++j) dp[j] = stag[b][j];
        }
    }
}

// exclusive scan of bucket counts -> bbase; rowptr[N] = E_total
__global__ __launch_bounds__(64) void scanb_k(const int* __restrict__ gcur,
                                              int* __restrict__ bbase,
                                              int* __restrict__ rowptr_end) {
    if (threadIdx.x == 0) {
        int acc = 0;
        for (int i = 0; i < NB; ++i) { bbase[i] = acc; acc += gcur[i]; }
        *rowptr_end = acc;
    }
}

// One block per bucket: histogram -> scan -> counting-sort in LDS -> stream out.
// Also writes rowptr and dinv for the bucket's nodes.
__global__ __launch_bounds__(256) void build_k(
    const unsigned* __restrict__ recs, const int* __restrict__ gcur,
    const int* __restrict__ bbase, int* __restrict__ rowptr,
    int* __restrict__ csr, float* __restrict__ dinv, int N) {
    __shared__ int cnt[256];
    __shared__ int scan[256];
    __shared__ int lpos[256];
    __shared__ int lcsr[CAPR];
    const int t = threadIdx.x;
    const int b = blockIdx.x;
    const int n0 = b << BSH;
    const int nn = min(256, N - n0);
    const int tb = gcur[b];
    const int gbase = bbase[b];
    const size_t rbase = (size_t)b * CAPR;

    cnt[t] = 0;
    __syncthreads();
    for (int i = t; i < tb; i += 256) atomicAdd(&cnt[recs[rbase + i] >> 17], 1);
    __syncthreads();

    scan[t] = cnt[t];
    __syncthreads();
    for (int o = 1; o < 256; o <<= 1) {
        int x = (t >= o) ? scan[t - o] : 0;
        __syncthreads(); scan[t] += x; __syncthreads();
    }
    const int excl = scan[t] - cnt[t];
    lpos[t] = excl;
    if (t < nn) {
        rowptr[n0 + t] = gbase + excl;
        dinv[n0 + t] = rsqrtf((float)(cnt[t] + 1));  // +1 = self loop
    }
    __syncthreads();

    for (int i = t; i < tb; i += 256) {
        const unsigned r = recs[rbase + i];
        const int p = atomicAdd(&lpos[r >> 17], 1);
        lcsr[p] = (int)(r & 0x1FFFFu);
    }
    __syncthreads();
    for (int i = t; i < tb; i += 256) csr[gbase + i] = lcsr[i];
}

// W12 = W1 [128x128] @ W2 [128x64]; c2 = W2^T b1 [64]
__global__ __launch_bounds__(256) void w12_k(
    const float* __restrict__ W1, const float* __restrict__ W2,
    const float* __restrict__ b1, float* __restrict__ W12, float* __restrict__ c2) {
    const int t = threadIdx.x;
    if (blockIdx.x < 32) {
        const int r = blockIdx.x * 4 + (t >> 6);
        const int c = t & 63;
        float acc = 0.f;
        for (int k = 0; k < 128; ++k) acc += W1[r * 128 + k] * W2[k * 64 + c];
        W12[r * 64 + c] = acc;
    } else if (t < 64) {
        float acc = 0.f;
        for (int k = 0; k < 128; ++k) acc += b1[k] * W2[k * 64 + t];
        c2[t] = acc;
    }
}

// g = dinv * (X [N,128] @ W [128,64]); 16 rows x 64 cols per block.
__global__ __launch_bounds__(256) void gemm_scale_k(
    const float* __restrict__ X, const float* __restrict__ W,
    const float* __restrict__ dinv, float* __restrict__ g, int N) {
    __shared__ float Ws[64 * 64];
    __shared__ float Xs[16 * 128];

    const int t = threadIdx.x;
    const int row0 = blockIdx.x * 16;

    for (int i = t; i < 16 * 128; i += 256) {
        int r = i >> 7, k = i & 127;
        int gr = row0 + r;
        Xs[i] = (gr < N) ? X[(size_t)gr * 128 + k] : 0.0f;
    }

    const int c  = t & 63;
    const int rg = t >> 6;

    float acc[4] = {0.f, 0.f, 0.f, 0.f};

    for (int kc = 0; kc < 2; ++kc) {
        for (int i = t; i < 64 * 64; i += 256) Ws[i] = W[kc * 64 * 64 + i];
        __syncthreads();
#pragma unroll 4
        for (int kk = 0; kk < 64; ++kk) {
            const int k = kc * 64 + kk;
            const float w = Ws[kk * 64 + c];
#pragma unroll
            for (int i = 0; i < 4; ++i)
                acc[i] += Xs[(rg * 4 + i) * 128 + k] * w;
        }
        __syncthreads();
    }

#pragma unroll
    for (int i = 0; i < 4; ++i) {
        int gr = row0 + rg * 4 + i;
        if (gr < N) g[(size_t)gr * 64 + c] = acc[i] * dinv[gr];
    }
}

// Wave-per-node CSR gather. lane = feature (64 feats).
// PASS2=0: outp[d] = dinv[d]^2 * (gin[d] + sum_nbr gin[s]);
//          p[d]    = dinv[d] * (dinv[d] + sum_nbr dinv[s]).
// PASS2=1: outp[d] = dinv[d] * (gin[d] + sum_nbr gin[s]) + p[d]*c2 + b2.
template <int PASS2>
__global__ __launch_bounds__(256) void agg_k(
    const float* __restrict__ gin, const int* __restrict__ rowptr,
    const int* __restrict__ csr, const float* __restrict__ dinv,
    float* __restrict__ outp, float* __restrict__ p,
    const float* __restrict__ c2, const float* __restrict__ b2, int N) {
    const int d = (blockIdx.x * 256 + threadIdx.x) >> 6;
    const int lane = threadIdx.x & 63;
    if (d >= N) return;
    const int beg = rowptr[d], end = rowptr[d + 1];
    const float di = dinv[d];

    float acc = gin[(size_t)d * 64 + lane];
    float accp = PASS2 ? 0.f : di;

    int e = beg;
    for (; e + 4 <= end; e += 4) {
        const int s0 = csr[e];
        const int s1 = csr[e + 1];
        const int s2 = csr[e + 2];
        const int s3 = csr[e + 3];
        const float v0 = gin[(size_t)s0 * 64 + lane];
        const float v1 = gin[(size_t)s1 * 64 + lane];
        const float v2 = gin[(size_t)s2 * 64 + lane];
        const float v3 = gin[(size_t)s3 * 64 + lane];
        if (!PASS2) accp += (dinv[s0] + dinv[s1]) + (dinv[s2] + dinv[s3]);
        acc += (v0 + v1) + (v2 + v3);
    }
    for (; e < end; ++e) {
        const int s = csr[e];
        if (!PASS2) accp += dinv[s];
        acc += gin[(size_t)s * 64 + lane];
    }

    if (PASS2) {
        outp[(size_t)d * 64 + lane] = acc * di + p[d] * c2[lane] + b2[lane];
    } else {
        outp[(size_t)d * 64 + lane] = acc * di * di;  // pre-scaled for hop 2
        if (lane == 0) p[d] = di * accp;
    }
}

extern "C" void kernel_launch(void* const* d_in, const int* in_sizes, int n_in,
                              void* d_out, int out_size, void* d_ws, size_t ws_size,
                              hipStream_t stream) {
    const float* x  = (const float*)d_in[0];
    const int*   ei = (const int*)d_in[1];
    const float* W1 = (const float*)d_in[2];
    const float* b1 = (const float*)d_in[3];
    const float* W2 = (const float*)d_in[4];
    const float* b2 = (const float*)d_in[5];
    float* out = (float*)d_out;

    const int N = in_sizes[0] / 128;   // 100000
    const int E = in_sizes[1] / 2;     // 3200000
    const int* src = ei;
    const int* dst = ei + E;

    char* ws = (char*)d_ws;
    auto take = [&](size_t bytes) { char* q = ws; ws += (bytes + 255) & ~(size_t)255; return q; };
    int*      gcur   = (int*)     take(NB * 4);
    int*      bbase  = (int*)     take(NB * 4);
    int*      rowptr = (int*)     take((size_t)(N + 1) * 4);
    float*    dinv   = (float*)   take((size_t)N * 4);
    float*    pbuf   = (float*)   take((size_t)N * 4);
    float*    W12    = (float*)   take(128 * 64 * 4);
    float*    c2     = (float*)   take(64 * 4);
    unsigned* recs   = (unsigned*)take((size_t)NB * CAPR * 4);
    int*      csr    = (int*)     take((size_t)E * 4);
    float*    g      = (float*)   take((size_t)N * 64 * 4);
    float*    t1     = (float*)   take((size_t)N * 64 * 4);

    hipMemsetAsync(gcur, 0, NB * 4, stream);

    partition_k<<<PBLK, 256, 0, stream>>>(src, dst, gcur, recs, E);
    scanb_k<<<1, 64, 0, stream>>>(gcur, bbase, rowptr + N);
    build_k<<<NB, 256, 0, stream>>>(recs, gcur, bbase, rowptr, csr, dinv, N);
    w12_k<<<33, 256, 0, stream>>>(W1, W2, b1, W12, c2);
    gemm_scale_k<<<(N + 15) / 16, 256, 0, stream>>>(x, W12, dinv, g, N);

    const int aggBlocks = (int)(((size_t)N * 64 + 255) / 256);
    agg_k<0><<<aggBlocks, 256, 0, stream>>>(g,  rowptr, csr, dinv, t1,  pbuf, c2, b2, N);
    agg_k<1><<<aggBlocks, 256, 0, stream>>>(t1, rowptr, csr, dinv, out, pbuf, c2, b2, N);
}

// Round 5
// 492.216 us; speedup vs baseline: 6.6972x; 1.1908x over previous
//
#include <hip/hip_runtime.h>
#include <cstdint>
#include <cstddef>

// ---------------------------------------------------------------------------
// GCN 2-layer forward — linear-network restructure:
//   out = Â·(Â·(X·W12)) + p·c2ᵀ + 1·b2ᵀ,  W12 = W1·W2, c2 = W2ᵀ·b1, p = Â·1
// CSR built via two-pass counting sort with dense per-(block,bucket) staging
// (every HBM line has a single writer); aggregation via wave-per-node
// register-accumulator gather (no atomics).
// ---------------------------------------------------------------------------

#define NB    391     // buckets of 256 dst nodes (N = 100000 -> 391)
#define BSH   8
#define CAPS  32      // LDS stage slots per (block,bucket); Poisson(16) fits
#define PBLK  512     // partition blocks (2 per CU)
#define OVCAP 4096    // per-bucket overflow region (expected use ~0)
#define CAPB  9216    // per-bucket CSR cap (mean 8184, sigma ~90)

// record: (dst & 255) << 17 | src   (src < 2^17)

__global__ __launch_bounds__(256) void partition_k(
    const int* __restrict__ src, const int* __restrict__ dst,
    int* __restrict__ ovcur, unsigned* __restrict__ ovrecs,
    unsigned* __restrict__ tailbuf, int* __restrict__ tailcnt, int E) {
    __shared__ unsigned stag[NB][CAPS];
    __shared__ int scnt[NB];
    const int t = threadIdx.x;
    for (int i = t; i < NB; i += 256) scnt[i] = 0;
    __syncthreads();

    const int Q = E >> 2;                       // full int4 quads
    const int per = (Q + PBLK - 1) / PBLK;
    const int qbeg = blockIdx.x * per;
    const int qend = min(qbeg + per, Q);
    const int4* src4 = (const int4*)src;
    const int4* dst4 = (const int4*)dst;

    for (int q = qbeg + t; q < qend; q += 256) {
        const int4 s4 = src4[q];
        const int4 d4 = dst4[q];
#pragma unroll
        for (int j = 0; j < 4; ++j) {
            const int s = (&s4.x)[j], d = (&d4.x)[j];
            const int b = d >> BSH;
            const unsigned rec = ((unsigned)(d & 255) << 17) | (unsigned)s;
            const int slot = atomicAdd(&scnt[b], 1);
            if (slot < CAPS) stag[b][slot] = rec;
            else { const int p = atomicAdd(&ovcur[b], 1); ovrecs[(size_t)b * OVCAP + p] = rec; }
        }
    }
    if (blockIdx.x == 0) {                      // E % 4 remainder
        for (int e = (E & ~3) + t; e < E; e += 256) {
            const int s = src[e], d = dst[e];
            const int b = d >> BSH;
            const unsigned rec = ((unsigned)(d & 255) << 17) | (unsigned)s;
            const int slot = atomicAdd(&scnt[b], 1);
            if (slot < CAPS) stag[b][slot] = rec;
            else { const int p = atomicAdd(&ovcur[b], 1); ovrecs[(size_t)b * OVCAP + p] = rec; }
        }
    }
    __syncthreads();

    // dense coalesced dump: lane j of 32 reads stag[b][j] (consecutive words,
    // conflict-free) and writes one 128B line per (b,block).
    for (int i = t; i < NB * CAPS; i += 256) {
        const int b = i >> 5, j = i & 31;
        if (j < min(scnt[b], CAPS))
            tailbuf[((size_t)b * PBLK + blockIdx.x) * CAPS + j] = stag[b][j];
    }
    for (int b = t; b < NB; b += 256)
        tailcnt[b * PBLK + blockIdx.x] = min(scnt[b], CAPS);
}

// total[b] = ovcur[b] + sum_blk tailcnt[b][blk]   (one block per bucket)
__global__ __launch_bounds__(256) void totals_k(const int* __restrict__ ovcur,
                                                const int* __restrict__ tailcnt,
                                                int* __restrict__ total) {
    __shared__ int sh[256];
    const int b = blockIdx.x, t = threadIdx.x;
    int acc = 0;
    for (int i = t; i < PBLK; i += 256) acc += tailcnt[b * PBLK + i];
    sh[t] = acc; __syncthreads();
    for (int o = 128; o > 0; o >>= 1) { if (t < o) sh[t] += sh[t + o]; __syncthreads(); }
    if (t == 0) total[b] = sh[0] + ovcur[b];
}

// exclusive scan of 391 bucket totals (single block, Hillis-Steele)
__global__ __launch_bounds__(512) void scanb_k(const int* __restrict__ total,
                                               int* __restrict__ bbase,
                                               int* __restrict__ rowptr_end) {
    __shared__ int sh[512];
    const int t = threadIdx.x;
    sh[t] = (t < NB) ? total[t] : 0;
    __syncthreads();
    for (int o = 1; o < 512; o <<= 1) {
        int x = (t >= o) ? sh[t - o] : 0;
        __syncthreads(); sh[t] += x; __syncthreads();
    }
    if (t < NB) bbase[t] = sh[t] - total[t];
    if (t == NB - 1) *rowptr_end = sh[t];
}

// One block per bucket: histogram -> scan -> counting-sort in LDS -> stream out.
__global__ __launch_bounds__(256) void build_k(
    const unsigned* __restrict__ ovrecs, const int* __restrict__ ovcur,
    const unsigned* __restrict__ tailbuf, const int* __restrict__ tailcnt,
    const int* __restrict__ bbase, int* __restrict__ rowptr,
    int* __restrict__ csr, float* __restrict__ dinv, int N) {
    __shared__ int cnt[256];
    __shared__ int scan[256];
    __shared__ int lpos[256];
    __shared__ int tcs[PBLK];
    __shared__ int lcsr[CAPB];
    const int t = threadIdx.x, b = blockIdx.x;
    const int n0 = b << BSH;
    const int nn = min(256, N - n0);
    const int gbase = bbase[b];
    const size_t tb0 = (size_t)b * PBLK * CAPS;
    const int ov = ovcur[b];

    cnt[t] = 0;
    for (int i = t; i < PBLK; i += 256) tcs[i] = tailcnt[b * PBLK + i];
    __syncthreads();

    for (int i = t; i < PBLK * CAPS; i += 256) {
        if ((i & 31) < tcs[i >> 5]) atomicAdd(&cnt[tailbuf[tb0 + i] >> 17], 1);
    }
    for (int i = t; i < ov; i += 256) atomicAdd(&cnt[ovrecs[(size_t)b * OVCAP + i] >> 17], 1);
    __syncthreads();

    scan[t] = cnt[t];
    __syncthreads();
    for (int o = 1; o < 256; o <<= 1) {
        int x = (t >= o) ? scan[t - o] : 0;
        __syncthreads(); scan[t] += x; __syncthreads();
    }
    const int excl = scan[t] - cnt[t];
    lpos[t] = excl;
    if (t < nn) {
        rowptr[n0 + t] = gbase + excl;
        dinv[n0 + t] = rsqrtf((float)(cnt[t] + 1));  // +1 = self loop
    }
    __syncthreads();

    for (int i = t; i < PBLK * CAPS; i += 256) {
        if ((i & 31) < tcs[i >> 5]) {
            const unsigned r = tailbuf[tb0 + i];
            const int p = atomicAdd(&lpos[r >> 17], 1);
            lcsr[p] = (int)(r & 0x1FFFFu);
        }
    }
    for (int i = t; i < ov; i += 256) {
        const unsigned r = ovrecs[(size_t)b * OVCAP + i];
        const int p = atomicAdd(&lpos[r >> 17], 1);
        lcsr[p] = (int)(r & 0x1FFFFu);
    }
    __syncthreads();

    const int tot = scan[255];
    for (int i = t; i < tot; i += 256) csr[gbase + i] = lcsr[i];
}

// W12 = W1 [128x128] @ W2 [128x64]; c2 = W2^T b1 [64]
__global__ __launch_bounds__(256) void w12_k(
    const float* __restrict__ W1, const float* __restrict__ W2,
    const float* __restrict__ b1, float* __restrict__ W12, float* __restrict__ c2) {
    const int t = threadIdx.x;
    if (blockIdx.x < 32) {
        const int r = blockIdx.x * 4 + (t >> 6);
        const int c = t & 63;
        float acc = 0.f;
        for (int k = 0; k < 128; ++k) acc += W1[r * 128 + k] * W2[k * 64 + c];
        W12[r * 64 + c] = acc;
    } else if (t < 64) {
        float acc = 0.f;
        for (int k = 0; k < 128; ++k) acc += b1[k] * W2[k * 64 + t];
        c2[t] = acc;
    }
}

// g = dinv * (X [N,128] @ W [128,64]); 16 rows x 64 cols per block.
__global__ __launch_bounds__(256) void gemm_scale_k(
    const float* __restrict__ X, const float* __restrict__ W,
    const float* __restrict__ dinv, float* __restrict__ g, int N) {
    __shared__ float Ws[64 * 64];
    __shared__ float Xs[16 * 128];

    const int t = threadIdx.x;
    const int row0 = blockIdx.x * 16;

    for (int i = t; i < 16 * 128; i += 256) {
        int r = i >> 7, k = i & 127;
        int gr = row0 + r;
        Xs[i] = (gr < N) ? X[(size_t)gr * 128 + k] : 0.0f;
    }

    const int c  = t & 63;
    const int rg = t >> 6;

    float acc[4] = {0.f, 0.f, 0.f, 0.f};

    for (int kc = 0; kc < 2; ++kc) {
        for (int i = t; i < 64 * 64; i += 256) Ws[i] = W[kc * 64 * 64 + i];
        __syncthreads();
#pragma unroll 4
        for (int kk = 0; kk < 64; ++kk) {
            const int k = kc * 64 + kk;
            const float w = Ws[kk * 64 + c];
#pragma unroll
            for (int i = 0; i < 4; ++i)
                acc[i] += Xs[(rg * 4 + i) * 128 + k] * w;
        }
        __syncthreads();
    }

#pragma unroll
    for (int i = 0; i < 4; ++i) {
        int gr = row0 + rg * 4 + i;
        if (gr < N) g[(size_t)gr * 64 + c] = acc[i] * dinv[gr];
    }
}

// Wave-per-node CSR gather. lane = feature (64 feats).
// PASS2=0: outp[d] = dinv[d]^2 * (gin[d] + sum_nbr gin[s]);
//          p[d]    = dinv[d] * (dinv[d] + sum_nbr dinv[s]).
// PASS2=1: outp[d] = dinv[d] * (gin[d] + sum_nbr gin[s]) + p[d]*c2 + b2.
template <int PASS2>
__global__ __launch_bounds__(256) void agg_k(
    const float* __restrict__ gin, const int* __restrict__ rowptr,
    const int* __restrict__ csr, const float* __restrict__ dinv,
    float* __restrict__ outp, float* __restrict__ p,
    const float* __restrict__ c2, const float* __restrict__ b2, int N) {
    const int d = (blockIdx.x * 256 + threadIdx.x) >> 6;
    const int lane = threadIdx.x & 63;
    if (d >= N) return;
    const int beg = rowptr[d], end = rowptr[d + 1];
    const float di = dinv[d];

    float acc = gin[(size_t)d * 64 + lane];
    float accp = PASS2 ? 0.f : di;

    int e = beg;
    for (; e + 4 <= end; e += 4) {
        const int s0 = csr[e];
        const int s1 = csr[e + 1];
        const int s2 = csr[e + 2];
        const int s3 = csr[e + 3];
        const float v0 = gin[(size_t)s0 * 64 + lane];
        const float v1 = gin[(size_t)s1 * 64 + lane];
        const float v2 = gin[(size_t)s2 * 64 + lane];
        const float v3 = gin[(size_t)s3 * 64 + lane];
        if (!PASS2) accp += (dinv[s0] + dinv[s1]) + (dinv[s2] + dinv[s3]);
        acc += (v0 + v1) + (v2 + v3);
    }
    for (; e < end; ++e) {
        const int s = csr[e];
        if (!PASS2) accp += dinv[s];
        acc += gin[(size_t)s * 64 + lane];
    }

    if (PASS2) {
        outp[(size_t)d * 64 + lane] = acc * di + p[d] * c2[lane] + b2[lane];
    } else {
        outp[(size_t)d * 64 + lane] = acc * di * di;  // pre-scaled for hop 2
        if (lane == 0) p[d] = di * accp;
    }
}

extern "C" void kernel_launch(void* const* d_in, const int* in_sizes, int n_in,
                              void* d_out, int out_size, void* d_ws, size_t ws_size,
                              hipStream_t stream) {
    const float* x  = (const float*)d_in[0];
    const int*   ei = (const int*)d_in[1];
    const float* W1 = (const float*)d_in[2];
    const float* b1 = (const float*)d_in[3];
    const float* W2 = (const float*)d_in[4];
    const float* b2 = (const float*)d_in[5];
    float* out = (float*)d_out;

    const int N = in_sizes[0] / 128;   // 100000
    const int E = in_sizes[1] / 2;     // 3200000
    const int* src = ei;
    const int* dst = ei + E;

    char* ws = (char*)d_ws;
    auto take = [&](size_t bytes) { char* q = ws; ws += (bytes + 255) & ~(size_t)255; return q; };
    int*      ovcur   = (int*)     take(NB * 4);
    int*      total   = (int*)     take(NB * 4);
    int*      bbase   = (int*)     take(NB * 4);
    int*      rowptr  = (int*)     take((size_t)(N + 1) * 4);
    float*    dinv    = (float*)   take((size_t)N * 4);
    float*    pbuf    = (float*)   take((size_t)N * 4);
    float*    W12     = (float*)   take(128 * 64 * 4);
    float*    c2      = (float*)   take(64 * 4);
    int*      tailcnt = (int*)     take((size_t)NB * PBLK * 4);
    unsigned* ovrecs  = (unsigned*)take((size_t)NB * OVCAP * 4);
    unsigned* tailbuf = (unsigned*)take((size_t)NB * PBLK * CAPS * 4);
    int*      csr     = (int*)     take((size_t)E * 4);
    float*    g       = (float*)   take((size_t)N * 64 * 4);
    float*    t1      = (float*)   take((size_t)N * 64 * 4);

    hipMemsetAsync(ovcur, 0, NB * 4, stream);

    partition_k<<<PBLK, 256, 0, stream>>>(src, dst, ovcur, ovrecs, tailbuf, tailcnt, E);
    totals_k<<<NB, 256, 0, stream>>>(ovcur, tailcnt, total);
    scanb_k<<<1, 512, 0, stream>>>(total, bbase, rowptr + N);
    build_k<<<NB, 256, 0, stream>>>(ovrecs, ovcur, tailbuf, tailcnt, bbase, rowptr, csr, dinv, N);
    w12_k<<<33, 256, 0, stream>>>(W1, W2, b1, W12, c2);
    gemm_scale_k<<<(N + 15) / 16, 256, 0, stream>>>(x, W12, dinv, g, N);

    const int aggBlocks = (int)(((size_t)N * 64 + 255) / 256);
    agg_k<0><<<aggBlocks, 256, 0, stream>>>(g,  rowptr, csr, dinv, t1,  pbuf, c2, b2, N);
    agg_k<1><<<aggBlocks, 256, 0, stream>>>(t1, rowptr, csr, dinv, out, pbuf, c2, b2, N);
}

// Round 6
// 475.939 us; speedup vs baseline: 6.9262x; 1.0342x over previous
//
#include <hip/hip_runtime.h>
#include <hip/hip_fp16.h>
#include <cstdint>
#include <cstddef>

// ---------------------------------------------------------------------------
// GCN 2-layer forward — linear-network restructure:
//   out = Â·(Â·(X·W12)) + p·c2ᵀ + 1·b2ᵀ,  W12 = W1·W2, c2 = W2ᵀ·b1, p = Â·1
// CSR via two-pass counting sort (full-cacheline writes only). Aggregation is
// wave-per-node register gather; intermediate feature maps (g, t1) stored in
// f16 to halve gather traffic (the measured fabric-BW bottleneck).
// ---------------------------------------------------------------------------

#define NB    391     // buckets of 256 dst nodes (N = 100000 -> 391)
#define BSH   8
#define CAPS  32      // LDS stage slots per (block,bucket); Poisson(16) fits
#define PBLK  512     // partition blocks (2 per CU)
#define OVCAP 4096    // per-bucket overflow region (expected use ~0)
#define CAPB  9216    // per-bucket CSR cap (mean 8184, sigma ~90)

// record: (dst & 255) << 17 | src   (src < 2^17)

__global__ __launch_bounds__(256) void partition_k(
    const int* __restrict__ src, const int* __restrict__ dst,
    int* __restrict__ ovcur, unsigned* __restrict__ ovrecs,
    unsigned* __restrict__ tailbuf, int* __restrict__ tailcnt, int E) {
    __shared__ unsigned stag[NB][CAPS + 1];   // +1 pad: spread banks
    __shared__ int scnt[NB];
    const int t = threadIdx.x;
    for (int i = t; i < NB; i += 256) scnt[i] = 0;
    __syncthreads();

    const int Q = E >> 2;                       // full int4 quads
    const int per = (Q + PBLK - 1) / PBLK;
    const int qbeg = blockIdx.x * per;
    const int qend = min(qbeg + per, Q);
    const int4* src4 = (const int4*)src;
    const int4* dst4 = (const int4*)dst;

    for (int q = qbeg + t; q < qend; q += 256) {
        const int4 s4 = src4[q];
        const int4 d4 = dst4[q];
#pragma unroll
        for (int j = 0; j < 4; ++j) {
            const int s = (&s4.x)[j], d = (&d4.x)[j];
            const int b = d >> BSH;
            const unsigned rec = ((unsigned)(d & 255) << 17) | (unsigned)s;
            const int slot = atomicAdd(&scnt[b], 1);
            if (slot < CAPS) stag[b][slot] = rec;
            else { const int p = atomicAdd(&ovcur[b], 1); ovrecs[(size_t)b * OVCAP + p] = rec; }
        }
    }
    if (blockIdx.x == 0) {                      // E % 4 remainder
        for (int e = (E & ~3) + t; e < E; e += 256) {
            const int s = src[e], d = dst[e];
            const int b = d >> BSH;
            const unsigned rec = ((unsigned)(d & 255) << 17) | (unsigned)s;
            const int slot = atomicAdd(&scnt[b], 1);
            if (slot < CAPS) stag[b][slot] = rec;
            else { const int p = atomicAdd(&ovcur[b], 1); ovrecs[(size_t)b * OVCAP + p] = rec; }
        }
    }
    __syncthreads();

    // dense dump: 32 consecutive lanes write one full 128B line per bucket
    for (int i = t; i < NB * CAPS; i += 256) {
        const int b = i >> 5, j = i & 31;
        if (j < min(scnt[b], CAPS))
            tailbuf[((size_t)b * PBLK + blockIdx.x) * CAPS + j] = stag[b][j];
    }
    for (int b = t; b < NB; b += 256)           // transposed: coalesced write
        tailcnt[blockIdx.x * NB + b] = min(scnt[b], CAPS);
}

// total[b] = ovcur[b] + sum_blk tailcnt[blk][b]; exclusive scan -> bbase
__global__ __launch_bounds__(512) void totscan_k(
    const int* __restrict__ ovcur, const int* __restrict__ tailcnt,
    int* __restrict__ bbase, int* __restrict__ rowptr_end) {
    __shared__ int sh[512];
    const int t = threadIdx.x;
    int tot = 0;
    if (t < NB) {
        for (int i = 0; i < PBLK; ++i) tot += tailcnt[i * NB + t];
        tot += ovcur[t];
    }
    sh[t] = tot;
    __syncthreads();
    for (int o = 1; o < 512; o <<= 1) {
        int x = (t >= o) ? sh[t - o] : 0;
        __syncthreads(); sh[t] += x; __syncthreads();
    }
    if (t < NB) bbase[t] = sh[t] - tot;
    if (t == NB - 1) *rowptr_end = sh[t];
}

// One block per bucket: histogram -> scan -> counting-sort in LDS -> stream out.
__global__ __launch_bounds__(256) void build_k(
    const unsigned* __restrict__ ovrecs, const int* __restrict__ ovcur,
    const unsigned* __restrict__ tailbuf, const int* __restrict__ tailcnt,
    const int* __restrict__ bbase, int* __restrict__ rowptr,
    int* __restrict__ csr, float* __restrict__ dinv, int N) {
    __shared__ int cnt[256];
    __shared__ int scan[256];
    __shared__ int lpos[256];
    __shared__ int tcs[PBLK];
    __shared__ int lcsr[CAPB];
    const int t = threadIdx.x, b = blockIdx.x;
    const int n0 = b << BSH;
    const int nn = min(256, N - n0);
    const int gbase = bbase[b];
    const size_t tb0 = (size_t)b * PBLK * CAPS;
    const int ov = ovcur[b];

    cnt[t] = 0;
    for (int i = t; i < PBLK; i += 256) tcs[i] = tailcnt[i * NB + b];
    __syncthreads();

    for (int i = t; i < PBLK * CAPS; i += 256) {
        if ((i & 31) < tcs[i >> 5]) atomicAdd(&cnt[tailbuf[tb0 + i] >> 17], 1);
    }
    for (int i = t; i < ov; i += 256) atomicAdd(&cnt[ovrecs[(size_t)b * OVCAP + i] >> 17], 1);
    __syncthreads();

    scan[t] = cnt[t];
    __syncthreads();
    for (int o = 1; o < 256; o <<= 1) {
        int x = (t >= o) ? scan[t - o] : 0;
        __syncthreads(); scan[t] += x; __syncthreads();
    }
    const int excl = scan[t] - cnt[t];
    lpos[t] = excl;
    if (t < nn) {
        rowptr[n0 + t] = gbase + excl;
        dinv[n0 + t] = rsqrtf((float)(cnt[t] + 1));  // +1 = self loop
    }
    __syncthreads();

    for (int i = t; i < PBLK * CAPS; i += 256) {
        if ((i & 31) < tcs[i >> 5]) {
            const unsigned r = tailbuf[tb0 + i];
            const int p = atomicAdd(&lpos[r >> 17], 1);
            lcsr[p] = (int)(r & 0x1FFFFu);
        }
    }
    for (int i = t; i < ov; i += 256) {
        const unsigned r = ovrecs[(size_t)b * OVCAP + i];
        const int p = atomicAdd(&lpos[r >> 17], 1);
        lcsr[p] = (int)(r & 0x1FFFFu);
    }
    __syncthreads();

    const int tot = scan[255];
    for (int i = t; i < tot; i += 256) csr[gbase + i] = lcsr[i];
}

// W12 = W1 [128x128] @ W2 [128x64]; c2 = W2^T b1 [64]
__global__ __launch_bounds__(256) void w12_k(
    const float* __restrict__ W1, const float* __restrict__ W2,
    const float* __restrict__ b1, float* __restrict__ W12, float* __restrict__ c2) {
    const int t = threadIdx.x;
    if (blockIdx.x < 32) {
        const int r = blockIdx.x * 4 + (t >> 6);
        const int c = t & 63;
        float acc = 0.f;
        for (int k = 0; k < 128; ++k) acc += W1[r * 128 + k] * W2[k * 64 + c];
        W12[r * 64 + c] = acc;
    } else if (t < 64) {
        float acc = 0.f;
        for (int k = 0; k < 128; ++k) acc += b1[k] * W2[k * 64 + t];
        c2[t] = acc;
    }
}

// g = f16( dinv * (X [N,128] @ W [128,64]) ); 16 rows x 64 cols per block.
__global__ __launch_bounds__(256) void gemm_scale_k(
    const float* __restrict__ X, const float* __restrict__ W,
    const float* __restrict__ dinv, __half* __restrict__ g, int N) {
    __shared__ float Ws[64 * 64];
    __shared__ float Xs[16 * 128];

    const int t = threadIdx.x;
    const int row0 = blockIdx.x * 16;

    for (int i = t; i < 16 * 128; i += 256) {
        int r = i >> 7, k = i & 127;
        int gr = row0 + r;
        Xs[i] = (gr < N) ? X[(size_t)gr * 128 + k] : 0.0f;
    }

    const int c  = t & 63;
    const int rg = t >> 6;

    float acc[4] = {0.f, 0.f, 0.f, 0.f};

    for (int kc = 0; kc < 2; ++kc) {
        for (int i = t; i < 64 * 64; i += 256) Ws[i] = W[kc * 64 * 64 + i];
        __syncthreads();
#pragma unroll 4
        for (int kk = 0; kk < 64; ++kk) {
            const int k = kc * 64 + kk;
            const float w = Ws[kk * 64 + c];
#pragma unroll
            for (int i = 0; i < 4; ++i)
                acc[i] += Xs[(rg * 4 + i) * 128 + k] * w;
        }
        __syncthreads();
    }

#pragma unroll
    for (int i = 0; i < 4; ++i) {
        int gr = row0 + rg * 4 + i;
        if (gr < N) g[(size_t)gr * 64 + c] = __float2half(acc[i] * dinv[gr]);
    }
}

// Wave-per-node CSR gather over f16 rows (128 B/row; lanes 0-31 and 32-63
// load the same 32 half2 words -> coalescer fetches 128 B per edge).
// lane L handles feature f = 2*(L&31) + (L>>5).
// PASS2=0: t1[d] = f16( dinv[d]^2 * (g[d] + sum g[s]) );
//          p[d]  = dinv[d] * (dinv[d] + sum dinv[s]).
// PASS2=1: out[d] = dinv[d] * (t1[d] + sum t1[s]) + p[d]*c2 + b2  (f32).
template <int PASS2>
__global__ __launch_bounds__(256) void agg_k(
    const __half* __restrict__ gin, const int* __restrict__ rowptr,
    const int* __restrict__ csr, const float* __restrict__ dinv,
    void* __restrict__ outp, float* __restrict__ p,
    const float* __restrict__ c2, const float* __restrict__ b2, int N) {
    const int d = (blockIdx.x * 256 + threadIdx.x) >> 6;
    const int lane = threadIdx.x & 63;
    if (d >= N) return;
    const int pair = lane & 31;
    const int comp = lane >> 5;
    const int feat = (pair << 1) + comp;
    const int beg = rowptr[d], end = rowptr[d + 1];
    const float di = dinv[d];

    auto gat = [&](int s) -> float {
        const float2 f = __half22float2(((const __half2*)(gin + ((size_t)s << 6)))[pair]);
        return comp ? f.y : f.x;
    };

    float acc = gat(d);                 // self term
    float accp = PASS2 ? 0.f : di;

    int e = beg;
    for (; e + 4 <= end; e += 4) {
        const int s0 = csr[e];
        const int s1 = csr[e + 1];
        const int s2 = csr[e + 2];
        const int s3 = csr[e + 3];
        const float v0 = gat(s0);
        const float v1 = gat(s1);
        const float v2 = gat(s2);
        const float v3 = gat(s3);
        if (!PASS2) accp += (dinv[s0] + dinv[s1]) + (dinv[s2] + dinv[s3]);
        acc += (v0 + v1) + (v2 + v3);
    }
    for (; e < end; ++e) {
        const int s = csr[e];
        if (!PASS2) accp += dinv[s];
        acc += gat(s);
    }

    if (PASS2) {
        ((float*)outp)[((size_t)d << 6) + feat] = acc * di + p[d] * c2[feat] + b2[feat];
    } else {
        ((__half*)outp)[((size_t)d << 6) + feat] = __float2half(acc * di * di);
        if (lane == 0) p[d] = di * accp;
    }
}

extern "C" void kernel_launch(void* const* d_in, const int* in_sizes, int n_in,
                              void* d_out, int out_size, void* d_ws, size_t ws_size,
                              hipStream_t stream) {
    const float* x  = (const float*)d_in[0];
    const int*   ei = (const int*)d_in[1];
    const float* W1 = (const float*)d_in[2];
    const float* b1 = (const float*)d_in[3];
    const float* W2 = (const float*)d_in[4];
    const float* b2 = (const float*)d_in[5];
    float* out = (float*)d_out;

    const int N = in_sizes[0] / 128;   // 100000
    const int E = in_sizes[1] / 2;     // 3200000
    const int* src = ei;
    const int* dst = ei + E;

    char* ws = (char*)d_ws;
    auto take = [&](size_t bytes) { char* q = ws; ws += (bytes + 255) & ~(size_t)255; return q; };
    int*      ovcur   = (int*)     take(NB * 4);
    int*      bbase   = (int*)     take(NB * 4);
    int*      rowptr  = (int*)     take((size_t)(N + 1) * 4);
    float*    dinv    = (float*)   take((size_t)N * 4);
    float*    pbuf    = (float*)   take((size_t)N * 4);
    float*    W12     = (float*)   take(128 * 64 * 4);
    float*    c2      = (float*)   take(64 * 4);
    int*      tailcnt = (int*)     take((size_t)NB * PBLK * 4);
    unsigned* ovrecs  = (unsigned*)take((size_t)NB * OVCAP * 4);
    unsigned* tailbuf = (unsigned*)take((size_t)NB * PBLK * CAPS * 4);
    int*      csr     = (int*)     take((size_t)E * 4);
    __half*   g       = (__half*)  take((size_t)N * 64 * 2);
    __half*   t1      = (__half*)  take((size_t)N * 64 * 2);

    hipMemsetAsync(ovcur, 0, NB * 4, stream);

    partition_k<<<PBLK, 256, 0, stream>>>(src, dst, ovcur, ovrecs, tailbuf, tailcnt, E);
    totscan_k<<<1, 512, 0, stream>>>(ovcur, tailcnt, bbase, rowptr + N);
    build_k<<<NB, 256, 0, stream>>>(ovrecs, ovcur, tailbuf, tailcnt, bbase, rowptr, csr, dinv, N);
    w12_k<<<33, 256, 0, stream>>>(W1, W2, b1, W12, c2);
    gemm_scale_k<<<(N + 15) / 16, 256, 0, stream>>>(x, W12, dinv, g, N);

    const int aggBlocks = (int)(((size_t)N * 64 + 255) / 256);
    agg_k<0><<<aggBlocks, 256, 0, stream>>>(g,  rowptr, csr, dinv, t1,  pbuf, c2, b2, N);
    agg_k<1><<<aggBlocks, 256, 0, stream>>>(t1, rowptr, csr, dinv, out, pbuf, c2, b2, N);
}

// Round 7
// 453.748 us; speedup vs baseline: 7.2649x; 1.0489x over previous
//
#include <hip/hip_runtime.h>
#include <hip/hip_fp16.h>
#include <cstdint>
#include <cstddef>

// ---------------------------------------------------------------------------
// GCN 2-layer forward — linear-network restructure:
//   out = Â·(Â·(X·W12)) + p·c2ᵀ + 1·b2ᵀ,  W12 = W1·W2, c2 = W2ᵀ·b1, p = Â·1
// CSR via two-pass counting sort (full-cacheline writes only). Aggregation is
// wave-per-node gather over f16 rows, TWO edges per wave step (lanes 0-31 =
// edge e, lanes 32-63 = edge e+1; each lane owns 2 features as float2).
// ---------------------------------------------------------------------------

#define NB    391     // buckets of 256 dst nodes (N = 100000 -> 391)
#define BSH   8
#define CAPS  32      // LDS stage slots per (block,bucket); Poisson(16) fits
#define PBLK  512     // partition blocks (2 per CU)
#define OVCAP 4096    // per-bucket overflow region (expected use ~0)
#define CAPB  9216    // per-bucket CSR cap (mean 8184, sigma ~90)

// record: (dst & 255) << 17 | src   (src < 2^17)

__global__ __launch_bounds__(256) void partition_k(
    const int* __restrict__ src, const int* __restrict__ dst,
    int* __restrict__ ovcur, unsigned* __restrict__ ovrecs,
    unsigned* __restrict__ tailbuf, int* __restrict__ tailcnt, int E) {
    __shared__ unsigned stag[NB][CAPS + 1];   // +1 pad: spread banks
    __shared__ int scnt[NB];
    const int t = threadIdx.x;
    for (int i = t; i < NB; i += 256) scnt[i] = 0;
    __syncthreads();

    const int Q = E >> 2;                       // full int4 quads
    const int per = (Q + PBLK - 1) / PBLK;
    const int qbeg = blockIdx.x * per;
    const int qend = min(qbeg + per, Q);
    const int4* src4 = (const int4*)src;
    const int4* dst4 = (const int4*)dst;

    for (int q = qbeg + t; q < qend; q += 256) {
        const int4 s4 = src4[q];
        const int4 d4 = dst4[q];
#pragma unroll
        for (int j = 0; j < 4; ++j) {
            const int s = (&s4.x)[j], d = (&d4.x)[j];
            const int b = d >> BSH;
            const unsigned rec = ((unsigned)(d & 255) << 17) | (unsigned)s;
            const int slot = atomicAdd(&scnt[b], 1);
            if (slot < CAPS) stag[b][slot] = rec;
            else { const int p = atomicAdd(&ovcur[b], 1); ovrecs[(size_t)b * OVCAP + p] = rec; }
        }
    }
    if (blockIdx.x == 0) {                      // E % 4 remainder
        for (int e = (E & ~3) + t; e < E; e += 256) {
            const int s = src[e], d = dst[e];
            const int b = d >> BSH;
            const unsigned rec = ((unsigned)(d & 255) << 17) | (unsigned)s;
            const int slot = atomicAdd(&scnt[b], 1);
            if (slot < CAPS) stag[b][slot] = rec;
            else { const int p = atomicAdd(&ovcur[b], 1); ovrecs[(size_t)b * OVCAP + p] = rec; }
        }
    }
    __syncthreads();

    // dense dump: 32 consecutive lanes write one full 128B line per bucket
    for (int i = t; i < NB * CAPS; i += 256) {
        const int b = i >> 5, j = i & 31;
        if (j < min(scnt[b], CAPS))
            tailbuf[((size_t)b * PBLK + blockIdx.x) * CAPS + j] = stag[b][j];
    }
    for (int b = t; b < NB; b += 256)           // transposed: coalesced write
        tailcnt[blockIdx.x * NB + b] = min(scnt[b], CAPS);
}

// total[b] = ovcur[b] + sum_blk tailcnt[blk][b]; exclusive scan -> bbase
__global__ __launch_bounds__(512) void totscan_k(
    const int* __restrict__ ovcur, const int* __restrict__ tailcnt,
    int* __restrict__ bbase, int* __restrict__ rowptr_end) {
    __shared__ int sh[512];
    const int t = threadIdx.x;
    int tot = 0;
    if (t < NB) {
        for (int i = 0; i < PBLK; ++i) tot += tailcnt[i * NB + t];
        tot += ovcur[t];
    }
    sh[t] = tot;
    __syncthreads();
    for (int o = 1; o < 512; o <<= 1) {
        int x = (t >= o) ? sh[t - o] : 0;
        __syncthreads(); sh[t] += x; __syncthreads();
    }
    if (t < NB) bbase[t] = sh[t] - tot;
    if (t == NB - 1) *rowptr_end = sh[t];
}

// One block per bucket: histogram -> scan -> counting-sort in LDS -> stream out.
__global__ __launch_bounds__(256) void build_k(
    const unsigned* __restrict__ ovrecs, const int* __restrict__ ovcur,
    const unsigned* __restrict__ tailbuf, const int* __restrict__ tailcnt,
    const int* __restrict__ bbase, int* __restrict__ rowptr,
    int* __restrict__ csr, float* __restrict__ dinv, int N) {
    __shared__ int cnt[256];
    __shared__ int scan[256];
    __shared__ int lpos[256];
    __shared__ int tcs[PBLK];
    __shared__ int lcsr[CAPB];
    const int t = threadIdx.x, b = blockIdx.x;
    const int n0 = b << BSH;
    const int nn = min(256, N - n0);
    const int gbase = bbase[b];
    const size_t tb0 = (size_t)b * PBLK * CAPS;
    const int ov = ovcur[b];

    cnt[t] = 0;
    for (int i = t; i < PBLK; i += 256) tcs[i] = tailcnt[i * NB + b];
    __syncthreads();

    for (int i = t; i < PBLK * CAPS; i += 256) {
        if ((i & 31) < tcs[i >> 5]) atomicAdd(&cnt[tailbuf[tb0 + i] >> 17], 1);
    }
    for (int i = t; i < ov; i += 256) atomicAdd(&cnt[ovrecs[(size_t)b * OVCAP + i] >> 17], 1);
    __syncthreads();

    scan[t] = cnt[t];
    __syncthreads();
    for (int o = 1; o < 256; o <<= 1) {
        int x = (t >= o) ? scan[t - o] : 0;
        __syncthreads(); scan[t] += x; __syncthreads();
    }
    const int excl = scan[t] - cnt[t];
    lpos[t] = excl;
    if (t < nn) {
        rowptr[n0 + t] = gbase + excl;
        dinv[n0 + t] = rsqrtf((float)(cnt[t] + 1));  // +1 = self loop
    }
    __syncthreads();

    for (int i = t; i < PBLK * CAPS; i += 256) {
        if ((i & 31) < tcs[i >> 5]) {
            const unsigned r = tailbuf[tb0 + i];
            const int p = atomicAdd(&lpos[r >> 17], 1);
            lcsr[p] = (int)(r & 0x1FFFFu);
        }
    }
    for (int i = t; i < ov; i += 256) {
        const unsigned r = ovrecs[(size_t)b * OVCAP + i];
        const int p = atomicAdd(&lpos[r >> 17], 1);
        lcsr[p] = (int)(r & 0x1FFFFu);
    }
    __syncthreads();

    const int tot = scan[255];
    for (int i = t; i < tot; i += 256) csr[gbase + i] = lcsr[i];
}

// W12 = W1 [128x128] @ W2 [128x64]; c2 = W2^T b1 [64]
__global__ __launch_bounds__(256) void w12_k(
    const float* __restrict__ W1, const float* __restrict__ W2,
    const float* __restrict__ b1, float* __restrict__ W12, float* __restrict__ c2) {
    const int t = threadIdx.x;
    if (blockIdx.x < 32) {
        const int r = blockIdx.x * 4 + (t >> 6);
        const int c = t & 63;
        float acc = 0.f;
        for (int k = 0; k < 128; ++k) acc += W1[r * 128 + k] * W2[k * 64 + c];
        W12[r * 64 + c] = acc;
    } else if (t < 64) {
        float acc = 0.f;
        for (int k = 0; k < 128; ++k) acc += b1[k] * W2[k * 64 + t];
        c2[t] = acc;
    }
}

// g = f16( dinv * (X [N,128] @ W [128,64]) ); 16 rows x 64 cols per block.
__global__ __launch_bounds__(256) void gemm_scale_k(
    const float* __restrict__ X, const float* __restrict__ W,
    const float* __restrict__ dinv, __half* __restrict__ g, int N) {
    __shared__ float Ws[64 * 64];
    __shared__ float Xs[16 * 128];

    const int t = threadIdx.x;
    const int row0 = blockIdx.x * 16;

    for (int i = t; i < 16 * 128; i += 256) {
        int r = i >> 7, k = i & 127;
        int gr = row0 + r;
        Xs[i] = (gr < N) ? X[(size_t)gr * 128 + k] : 0.0f;
    }

    const int c  = t & 63;
    const int rg = t >> 6;

    float acc[4] = {0.f, 0.f, 0.f, 0.f};

    for (int kc = 0; kc < 2; ++kc) {
        for (int i = t; i < 64 * 64; i += 256) Ws[i] = W[kc * 64 * 64 + i];
        __syncthreads();
#pragma unroll 4
        for (int kk = 0; kk < 64; ++kk) {
            const int k = kc * 64 + kk;
            const float w = Ws[kk * 64 + c];
#pragma unroll
            for (int i = 0; i < 4; ++i)
                acc[i] += Xs[(rg * 4 + i) * 128 + k] * w;
        }
        __syncthreads();
    }

#pragma unroll
    for (int i = 0; i < 4; ++i) {
        int gr = row0 + rg * 4 + i;
        if (gr < N) g[(size_t)gr * 64 + c] = __float2half(acc[i] * dinv[gr]);
    }
}

// Wave-per-node CSR gather, 2 edges per step.
// lanes 0-31 = edge slot 0, lanes 32-63 = edge slot 1; lane owns features
// {2*pair, 2*pair+1} as float2 (pair = lane & 31). Cross-slot partials are
// combined with one shuffle at the end.
// PASS2=0: t1[d] = f16( dinv[d]^2 * (g[d] + sum g[s]) );
//          p[d]  = dinv[d] * (dinv[d] + sum dinv[s]).
// PASS2=1: out[d] = dinv[d] * (t1[d] + sum t1[s]) + p[d]*c2 + b2  (f32).
template <int PASS2>
__global__ __launch_bounds__(256) void agg_k(
    const __half* __restrict__ gin, const int* __restrict__ rowptr,
    const int* __restrict__ csr, const float* __restrict__ dinv,
    void* __restrict__ outp, float* __restrict__ p,
    const float* __restrict__ c2, const float* __restrict__ b2, int N) {
    const int d = (blockIdx.x * 256 + threadIdx.x) >> 6;
    const int lane = threadIdx.x & 63;
    if (d >= N) return;
    const int pair = lane & 31;   // half2 word within row
    const int sub  = lane >> 5;   // edge slot
    const int beg = rowptr[d], end = rowptr[d + 1];
    const float di = dinv[d];
    const __half2* g2 = (const __half2*)gin;

    // self row (added once, after cross-slot combine)
    const float2 fself = __half22float2(g2[((size_t)d << 5) + pair]);

    float accx = 0.f, accy = 0.f;
    float accp = (!PASS2 && sub == 0) ? di : 0.f;

    int e = beg;
    for (; e + 4 <= end; e += 4) {              // 4 edges / iter (2 per slot)
        const int sA = csr[e + sub];
        const int sB = csr[e + 2 + sub];
        const float2 fA = __half22float2(g2[((size_t)sA << 5) + pair]);
        const float2 fB = __half22float2(g2[((size_t)sB << 5) + pair]);
        if (!PASS2) accp += dinv[sA] + dinv[sB];
        accx += fA.x + fB.x;
        accy += fA.y + fB.y;
    }
    if (e + 2 <= end) {                         // 2-edge tail
        const int sA = csr[e + sub];
        const float2 fA = __half22float2(g2[((size_t)sA << 5) + pair]);
        if (!PASS2) accp += dinv[sA];
        accx += fA.x; accy += fA.y;
        e += 2;
    }
    if (e < end && sub == 0) {                  // odd-edge tail (slot 0 only)
        const int sA = csr[e];
        const float2 fA = __half22float2(g2[((size_t)sA << 5) + pair]);
        if (!PASS2) accp += dinv[sA];
        accx += fA.x; accy += fA.y;
    }

    // combine slot0+slot1: lanes 0-31 pull lane+32's partial
    accx += __shfl(accx, pair + 32);
    accy += __shfl(accy, pair + 32);
    if (!PASS2) accp += __shfl(accp, pair + 32);

    if (sub == 0) {
        accx += fself.x; accy += fself.y;
        if (PASS2) {
            const float2 cc = ((const float2*)c2)[pair];
            const float2 bb = ((const float2*)b2)[pair];
            const float pd = p[d];
            float2 o;
            o.x = accx * di + pd * cc.x + bb.x;
            o.y = accy * di + pd * cc.y + bb.y;
            ((float2*)outp)[((size_t)d << 5) + pair] = o;
        } else {
            const float sc = di * di;
            ((__half2*)outp)[((size_t)d << 5) + pair] =
                __floats2half2_rn(accx * sc, accy * sc);
            if (lane == 0) p[d] = di * accp;
        }
    }
}

extern "C" void kernel_launch(void* const* d_in, const int* in_sizes, int n_in,
                              void* d_out, int out_size, void* d_ws, size_t ws_size,
                              hipStream_t stream) {
    const float* x  = (const float*)d_in[0];
    const int*   ei = (const int*)d_in[1];
    const float* W1 = (const float*)d_in[2];
    const float* b1 = (const float*)d_in[3];
    const float* W2 = (const float*)d_in[4];
    const float* b2 = (const float*)d_in[5];
    float* out = (float*)d_out;

    const int N = in_sizes[0] / 128;   // 100000
    const int E = in_sizes[1] / 2;     // 3200000
    const int* src = ei;
    const int* dst = ei + E;

    char* ws = (char*)d_ws;
    auto take = [&](size_t bytes) { char* q = ws; ws += (bytes + 255) & ~(size_t)255; return q; };
    int*      ovcur   = (int*)     take(NB * 4);
    int*      bbase   = (int*)     take(NB * 4);
    int*      rowptr  = (int*)     take((size_t)(N + 1) * 4);
    float*    dinv    = (float*)   take((size_t)N * 4);
    float*    pbuf    = (float*)   take((size_t)N * 4);
    float*    W12     = (float*)   take(128 * 64 * 4);
    float*    c2      = (float*)   take(64 * 4);
    int*      tailcnt = (int*)     take((size_t)NB * PBLK * 4);
    unsigned* ovrecs  = (unsigned*)take((size_t)NB * OVCAP * 4);
    unsigned* tailbuf = (unsigned*)take((size_t)NB * PBLK * CAPS * 4);
    int*      csr     = (int*)     take((size_t)E * 4);
    __half*   g       = (__half*)  take((size_t)N * 64 * 2);
    __half*   t1      = (__half*)  take((size_t)N * 64 * 2);

    hipMemsetAsync(ovcur, 0, NB * 4, stream);

    partition_k<<<PBLK, 256, 0, stream>>>(src, dst, ovcur, ovrecs, tailbuf, tailcnt, E);
    totscan_k<<<1, 512, 0, stream>>>(ovcur, tailcnt, bbase, rowptr + N);
    build_k<<<NB, 256, 0, stream>>>(ovrecs, ovcur, tailbuf, tailcnt, bbase, rowptr, csr, dinv, N);
    w12_k<<<33, 256, 0, stream>>>(W1, W2, b1, W12, c2);
    gemm_scale_k<<<(N + 15) / 16, 256, 0, stream>>>(x, W12, dinv, g, N);

    const int aggBlocks = (int)(((size_t)N * 64 + 255) / 256);
    agg_k<0><<<aggBlocks, 256, 0, stream>>>(g,  rowptr, csr, dinv, t1,  pbuf, c2, b2, N);
    agg_k<1><<<aggBlocks, 256, 0, stream>>>(t1, rowptr, csr, dinv, out, pbuf, c2, b2, N);
}

// Round 8
// 385.036 us; speedup vs baseline: 8.5614x; 1.1785x over previous
//
#include <hip/hip_runtime.h>
#include <hip/hip_fp16.h>
#include <cstdint>
#include <cstddef>

// ---------------------------------------------------------------------------
// GCN 2-layer forward — linear-network restructure:
//   out = Â·(Â·(X·W12)) + p·c2ᵀ + 1·b2ᵀ,  W12 = W1·W2, c2 = W2ᵀ·b1, p = Â·1
// CSR via two-pass counting sort (full-cacheline writes only). Aggregation is
// wave-per-node gather over f16 rows; each wave-half owns a contiguous half
// of the edge list and runs an 8/4/1 unroll ladder for deep MLP.
// ---------------------------------------------------------------------------

#define NB    391     // buckets of 256 dst nodes (N = 100000 -> 391)
#define BSH   8
#define CAPS  32      // LDS stage slots per (block,bucket); Poisson(16) fits
#define PBLK  512     // partition blocks (2 per CU)
#define OVCAP 4096    // per-bucket overflow region (expected use ~0)
#define CAPB  9216    // per-bucket CSR cap (mean 8184, sigma ~90)

// record: (dst & 255) << 17 | src   (src < 2^17)

__global__ __launch_bounds__(256) void partition_k(
    const int* __restrict__ src, const int* __restrict__ dst,
    int* __restrict__ ovcur, unsigned* __restrict__ ovrecs,
    unsigned* __restrict__ tailbuf, int* __restrict__ tailcnt, int E) {
    __shared__ unsigned stag[NB][CAPS + 1];   // +1 pad: spread banks
    __shared__ int scnt[NB];
    const int t = threadIdx.x;
    for (int i = t; i < NB; i += 256) scnt[i] = 0;
    __syncthreads();

    const int Q = E >> 2;                       // full int4 quads
    const int per = (Q + PBLK - 1) / PBLK;
    const int qbeg = blockIdx.x * per;
    const int qend = min(qbeg + per, Q);
    const int4* src4 = (const int4*)src;
    const int4* dst4 = (const int4*)dst;

    for (int q = qbeg + t; q < qend; q += 256) {
        const int4 s4 = src4[q];
        const int4 d4 = dst4[q];
#pragma unroll
        for (int j = 0; j < 4; ++j) {
            const int s = (&s4.x)[j], d = (&d4.x)[j];
            const int b = d >> BSH;
            const unsigned rec = ((unsigned)(d & 255) << 17) | (unsigned)s;
            const int slot = atomicAdd(&scnt[b], 1);
            if (slot < CAPS) stag[b][slot] = rec;
            else { const int p = atomicAdd(&ovcur[b], 1); ovrecs[(size_t)b * OVCAP + p] = rec; }
        }
    }
    if (blockIdx.x == 0) {                      // E % 4 remainder
        for (int e = (E & ~3) + t; e < E; e += 256) {
            const int s = src[e], d = dst[e];
            const int b = d >> BSH;
            const unsigned rec = ((unsigned)(d & 255) << 17) | (unsigned)s;
            const int slot = atomicAdd(&scnt[b], 1);
            if (slot < CAPS) stag[b][slot] = rec;
            else { const int p = atomicAdd(&ovcur[b], 1); ovrecs[(size_t)b * OVCAP + p] = rec; }
        }
    }
    __syncthreads();

    // dense dump: 32 consecutive lanes write one full 128B line per bucket
    for (int i = t; i < NB * CAPS; i += 256) {
        const int b = i >> 5, j = i & 31;
        if (j < min(scnt[b], CAPS))
            tailbuf[((size_t)b * PBLK + blockIdx.x) * CAPS + j] = stag[b][j];
    }
    for (int b = t; b < NB; b += 256)           // transposed: coalesced write
        tailcnt[blockIdx.x * NB + b] = min(scnt[b], CAPS);
}

// total[b] = ovcur[b] + sum_blk tailcnt[blk][b]; exclusive scan -> bbase
__global__ __launch_bounds__(512) void totscan_k(
    const int* __restrict__ ovcur, const int* __restrict__ tailcnt,
    int* __restrict__ bbase, int* __restrict__ rowptr_end) {
    __shared__ int sh[512];
    const int t = threadIdx.x;
    int tot = 0;
    if (t < NB) {
        for (int i = 0; i < PBLK; ++i) tot += tailcnt[i * NB + t];
        tot += ovcur[t];
    }
    sh[t] = tot;
    __syncthreads();
    for (int o = 1; o < 512; o <<= 1) {
        int x = (t >= o) ? sh[t - o] : 0;
        __syncthreads(); sh[t] += x; __syncthreads();
    }
    if (t < NB) bbase[t] = sh[t] - tot;
    if (t == NB - 1) *rowptr_end = sh[t];
}

// One block per bucket: histogram -> scan -> counting-sort in LDS -> stream out.
__global__ __launch_bounds__(256) void build_k(
    const unsigned* __restrict__ ovrecs, const int* __restrict__ ovcur,
    const unsigned* __restrict__ tailbuf, const int* __restrict__ tailcnt,
    const int* __restrict__ bbase, int* __restrict__ rowptr,
    int* __restrict__ csr, float* __restrict__ dinv, int N) {
    __shared__ int cnt[256];
    __shared__ int scan[256];
    __shared__ int lpos[256];
    __shared__ int tcs[PBLK];
    __shared__ int lcsr[CAPB];
    const int t = threadIdx.x, b = blockIdx.x;
    const int n0 = b << BSH;
    const int nn = min(256, N - n0);
    const int gbase = bbase[b];
    const size_t tb0 = (size_t)b * PBLK * CAPS;
    const int ov = ovcur[b];

    cnt[t] = 0;
    for (int i = t; i < PBLK; i += 256) tcs[i] = tailcnt[i * NB + b];
    __syncthreads();

    for (int i = t; i < PBLK * CAPS; i += 256) {
        if ((i & 31) < tcs[i >> 5]) atomicAdd(&cnt[tailbuf[tb0 + i] >> 17], 1);
    }
    for (int i = t; i < ov; i += 256) atomicAdd(&cnt[ovrecs[(size_t)b * OVCAP + i] >> 17], 1);
    __syncthreads();

    scan[t] = cnt[t];
    __syncthreads();
    for (int o = 1; o < 256; o <<= 1) {
        int x = (t >= o) ? scan[t - o] : 0;
        __syncthreads(); scan[t] += x; __syncthreads();
    }
    const int excl = scan[t] - cnt[t];
    lpos[t] = excl;
    if (t < nn) {
        rowptr[n0 + t] = gbase + excl;
        dinv[n0 + t] = rsqrtf((float)(cnt[t] + 1));  // +1 = self loop
    }
    __syncthreads();

    for (int i = t; i < PBLK * CAPS; i += 256) {
        if ((i & 31) < tcs[i >> 5]) {
            const unsigned r = tailbuf[tb0 + i];
            const int p = atomicAdd(&lpos[r >> 17], 1);
            lcsr[p] = (int)(r & 0x1FFFFu);
        }
    }
    for (int i = t; i < ov; i += 256) {
        const unsigned r = ovrecs[(size_t)b * OVCAP + i];
        const int p = atomicAdd(&lpos[r >> 17], 1);
        lcsr[p] = (int)(r & 0x1FFFFu);
    }
    __syncthreads();

    const int tot = scan[255];
    for (int i = t; i < tot; i += 256) csr[gbase + i] = lcsr[i];
}

// W12 = W1 [128x128] @ W2 [128x64]; c2 = W2^T b1 [64]
__global__ __launch_bounds__(256) void w12_k(
    const float* __restrict__ W1, const float* __restrict__ W2,
    const float* __restrict__ b1, float* __restrict__ W12, float* __restrict__ c2) {
    const int t = threadIdx.x;
    if (blockIdx.x < 32) {
        const int r = blockIdx.x * 4 + (t >> 6);
        const int c = t & 63;
        float acc = 0.f;
        for (int k = 0; k < 128; ++k) acc += W1[r * 128 + k] * W2[k * 64 + c];
        W12[r * 64 + c] = acc;
    } else if (t < 64) {
        float acc = 0.f;
        for (int k = 0; k < 128; ++k) acc += b1[k] * W2[k * 64 + t];
        c2[t] = acc;
    }
}

// g = f16( dinv * (X [N,128] @ W [128,64]) ); 16 rows x 64 cols per block.
__global__ __launch_bounds__(256) void gemm_scale_k(
    const float* __restrict__ X, const float* __restrict__ W,
    const float* __restrict__ dinv, __half* __restrict__ g, int N) {
    __shared__ float Ws[64 * 64];
    __shared__ float Xs[16 * 128];

    const int t = threadIdx.x;
    const int row0 = blockIdx.x * 16;

    for (int i = t; i < 16 * 128; i += 256) {
        int r = i >> 7, k = i & 127;
        int gr = row0 + r;
        Xs[i] = (gr < N) ? X[(size_t)gr * 128 + k] : 0.0f;
    }

    const int c  = t & 63;
    const int rg = t >> 6;

    float acc[4] = {0.f, 0.f, 0.f, 0.f};

    for (int kc = 0; kc < 2; ++kc) {
        for (int i = t; i < 64 * 64; i += 256) Ws[i] = W[kc * 64 * 64 + i];
        __syncthreads();
#pragma unroll 4
        for (int kk = 0; kk < 64; ++kk) {
            const int k = kc * 64 + kk;
            const float w = Ws[kk * 64 + c];
#pragma unroll
            for (int i = 0; i < 4; ++i)
                acc[i] += Xs[(rg * 4 + i) * 128 + k] * w;
        }
        __syncthreads();
    }

#pragma unroll
    for (int i = 0; i < 4; ++i) {
        int gr = row0 + rg * 4 + i;
        if (gr < N) g[(size_t)gr * 64 + c] = __float2half(acc[i] * dinv[gr]);
    }
}

// Wave-per-node CSR gather. lanes 0-31 (slot 0) take the first half of the
// edge list, lanes 32-63 (slot 1) the second half — contiguous per slot.
// Each slot runs an 8/4/1 unroll ladder (up to 16 outstanding gathers/wave).
// lane owns features {2*pair, 2*pair+1} (pair = lane & 31); one shuffle
// combines the slot partials.
// PASS2=0: t1[d] = f16( dinv[d]^2 * (g[d] + sum g[s]) );
//          p[d]  = dinv[d] * (dinv[d] + sum dinv[s]).
// PASS2=1: out[d] = dinv[d] * (t1[d] + sum t1[s]) + p[d]*c2 + b2  (f32).
template <int PASS2>
__global__ __launch_bounds__(256) void agg_k(
    const __half* __restrict__ gin, const int* __restrict__ rowptr,
    const int* __restrict__ csr, const float* __restrict__ dinv,
    void* __restrict__ outp, float* __restrict__ p,
    const float* __restrict__ c2, const float* __restrict__ b2, int N) {
    const int d = (blockIdx.x * 256 + threadIdx.x) >> 6;
    const int lane = threadIdx.x & 63;
    if (d >= N) return;
    const int pair = lane & 31;   // half2 word within row
    const int sub  = lane >> 5;   // edge-list half
    const int beg = rowptr[d], end = rowptr[d + 1];
    const int mid = beg + ((end - beg + 1) >> 1);
    const float di = dinv[d];
    const __half2* g2 = (const __half2*)gin;

    const float2 fself = __half22float2(g2[((size_t)d << 5) + pair]);

    float accx = 0.f, accy = 0.f;
    float accp = (!PASS2 && sub == 0) ? di : 0.f;

    int e        = sub ? mid : beg;
    const int eE = sub ? end : mid;

    for (; e + 8 <= eE; e += 8) {
        int s[8];
#pragma unroll
        for (int j = 0; j < 8; ++j) s[j] = csr[e + j];
        float2 f[8];
#pragma unroll
        for (int j = 0; j < 8; ++j) f[j] = __half22float2(g2[((size_t)s[j] << 5) + pair]);
        if (!PASS2) {
#pragma unroll
            for (int j = 0; j < 8; ++j) accp += dinv[s[j]];
        }
#pragma unroll
        for (int j = 0; j < 8; ++j) { accx += f[j].x; accy += f[j].y; }
    }
    if (e + 4 <= eE) {
        int s[4];
#pragma unroll
        for (int j = 0; j < 4; ++j) s[j] = csr[e + j];
        float2 f[4];
#pragma unroll
        for (int j = 0; j < 4; ++j) f[j] = __half22float2(g2[((size_t)s[j] << 5) + pair]);
        if (!PASS2) {
#pragma unroll
            for (int j = 0; j < 4; ++j) accp += dinv[s[j]];
        }
#pragma unroll
        for (int j = 0; j < 4; ++j) { accx += f[j].x; accy += f[j].y; }
        e += 4;
    }
    for (; e < eE; ++e) {
        const int s = csr[e];
        const float2 f = __half22float2(g2[((size_t)s << 5) + pair]);
        if (!PASS2) accp += dinv[s];
        accx += f.x; accy += f.y;
    }

    // combine slot0+slot1: lanes 0-31 pull lane+32's partial
    accx += __shfl(accx, pair + 32);
    accy += __shfl(accy, pair + 32);
    if (!PASS2) accp += __shfl(accp, pair + 32);

    if (sub == 0) {
        accx += fself.x; accy += fself.y;
        if (PASS2) {
            const float2 cc = ((const float2*)c2)[pair];
            const float2 bb = ((const float2*)b2)[pair];
            const float pd = p[d];
            float2 o;
            o.x = accx * di + pd * cc.x + bb.x;
            o.y = accy * di + pd * cc.y + bb.y;
            ((float2*)outp)[((size_t)d << 5) + pair] = o;
        } else {
            const float sc = di * di;
            ((__half2*)outp)[((size_t)d << 5) + pair] =
                __floats2half2_rn(accx * sc, accy * sc);
            if (lane == 0) p[d] = di * accp;
        }
    }
}

extern "C" void kernel_launch(void* const* d_in, const int* in_sizes, int n_in,
                              void* d_out, int out_size, void* d_ws, size_t ws_size,
                              hipStream_t stream) {
    const float* x  = (const float*)d_in[0];
    const int*   ei = (const int*)d_in[1];
    const float* W1 = (const float*)d_in[2];
    const float* b1 = (const float*)d_in[3];
    const float* W2 = (const float*)d_in[4];
    const float* b2 = (const float*)d_in[5];
    float* out = (float*)d_out;

    const int N = in_sizes[0] / 128;   // 100000
    const int E = in_sizes[1] / 2;     // 3200000
    const int* src = ei;
    const int* dst = ei + E;

    char* ws = (char*)d_ws;
    auto take = [&](size_t bytes) { char* q = ws; ws += (bytes + 255) & ~(size_t)255; return q; };
    int*      ovcur   = (int*)     take(NB * 4);
    int*      bbase   = (int*)     take(NB * 4);
    int*      rowptr  = (int*)     take((size_t)(N + 1) * 4);
    float*    dinv    = (float*)   take((size_t)N * 4);
    float*    pbuf    = (float*)   take((size_t)N * 4);
    float*    W12     = (float*)   take(128 * 64 * 4);
    float*    c2      = (float*)   take(64 * 4);
    int*      tailcnt = (int*)     take((size_t)NB * PBLK * 4);
    unsigned* ovrecs  = (unsigned*)take((size_t)NB * OVCAP * 4);
    unsigned* tailbuf = (unsigned*)take((size_t)NB * PBLK * CAPS * 4);
    int*      csr     = (int*)     take((size_t)E * 4);
    __half*   g       = (__half*)  take((size_t)N * 64 * 2);
    __half*   t1      = (__half*)  take((size_t)N * 64 * 2);

    hipMemsetAsync(ovcur, 0, NB * 4, stream);

    partition_k<<<PBLK, 256, 0, stream>>>(src, dst, ovcur, ovrecs, tailbuf, tailcnt, E);
    totscan_k<<<1, 512, 0, stream>>>(ovcur, tailcnt, bbase, rowptr + N);
    build_k<<<NB, 256, 0, stream>>>(ovrecs, ovcur, tailbuf, tailcnt, bbase, rowptr, csr, dinv, N);
    w12_k<<<33, 256, 0, stream>>>(W1, W2, b1, W12, c2);
    gemm_scale_k<<<(N + 15) / 16, 256, 0, stream>>>(x, W12, dinv, g, N);

    const int aggBlocks = (int)(((size_t)N * 64 + 255) / 256);
    agg_k<0><<<aggBlocks, 256, 0, stream>>>(g,  rowptr, csr, dinv, t1,  pbuf, c2, b2, N);
    agg_k<1><<<aggBlocks, 256, 0, stream>>>(t1, rowptr, csr, dinv, out, pbuf, c2, b2, N);
}

// Round 9
// 362.565 us; speedup vs baseline: 9.0920x; 1.0620x over previous
//
#include <hip/hip_runtime.h>
#include <hip/hip_fp16.h>
#include <cstdint>
#include <cstddef>

// ---------------------------------------------------------------------------
// GCN 2-layer forward — linear-network restructure:
//   out = Â·(Â·(X·W12)) + p·c2ᵀ + 1·b2ᵀ,  W12 = W1·W2, c2 = W2ᵀ·b1, p = Â·1
// CSR via two-pass counting sort (full-cacheline writes only). GEMM X·W12 via
// MFMA f16 with exact 2-way operand split (hi+lo; 3 products -> f32-accurate).
// Aggregation: wave-per-node gather over f16 rows, 8/4/1 unroll ladder.
// ---------------------------------------------------------------------------

#define NB    391     // buckets of 256 dst nodes (N = 100000 -> 391)
#define BSH   8
#define CAPS  32      // LDS stage slots per (block,bucket); Poisson(16) fits
#define PBLK  512     // partition blocks (2 per CU)
#define OVCAP 4096    // per-bucket overflow region (expected use ~0)
#define CAPB  9216    // per-bucket CSR cap (mean 8184, sigma ~90)

typedef _Float16 half8 __attribute__((ext_vector_type(8)));
typedef float    floatx4 __attribute__((ext_vector_type(4)));

// record: (dst & 255) << 17 | src   (src < 2^17)

__global__ __launch_bounds__(256) void partition_k(
    const int* __restrict__ src, const int* __restrict__ dst,
    int* __restrict__ ovcur, unsigned* __restrict__ ovrecs,
    unsigned* __restrict__ tailbuf, int* __restrict__ tailcnt, int E) {
    __shared__ unsigned stag[NB][CAPS + 1];   // +1 pad: spread banks
    __shared__ int scnt[NB];
    const int t = threadIdx.x;
    for (int i = t; i < NB; i += 256) scnt[i] = 0;
    __syncthreads();

    const int Q = E >> 2;                       // full int4 quads
    const int per = (Q + PBLK - 1) / PBLK;
    const int qbeg = blockIdx.x * per;
    const int qend = min(qbeg + per, Q);
    const int4* src4 = (const int4*)src;
    const int4* dst4 = (const int4*)dst;

    for (int q = qbeg + t; q < qend; q += 256) {
        const int4 s4 = src4[q];
        const int4 d4 = dst4[q];
#pragma unroll
        for (int j = 0; j < 4; ++j) {
            const int s = (&s4.x)[j], d = (&d4.x)[j];
            const int b = d >> BSH;
            const unsigned rec = ((unsigned)(d & 255) << 17) | (unsigned)s;
            const int slot = atomicAdd(&scnt[b], 1);
            if (slot < CAPS) stag[b][slot] = rec;
            else { const int p = atomicAdd(&ovcur[b], 1); ovrecs[(size_t)b * OVCAP + p] = rec; }
        }
    }
    if (blockIdx.x == 0) {                      // E % 4 remainder
        for (int e = (E & ~3) + t; e < E; e += 256) {
            const int s = src[e], d = dst[e];
            const int b = d >> BSH;
            const unsigned rec = ((unsigned)(d & 255) << 17) | (unsigned)s;
            const int slot = atomicAdd(&scnt[b], 1);
            if (slot < CAPS) stag[b][slot] = rec;
            else { const int p = atomicAdd(&ovcur[b], 1); ovrecs[(size_t)b * OVCAP + p] = rec; }
        }
    }
    __syncthreads();

    // dense dump: 32 consecutive lanes write one full 128B line per bucket
    for (int i = t; i < NB * CAPS; i += 256) {
        const int b = i >> 5, j = i & 31;
        if (j < min(scnt[b], CAPS))
            tailbuf[((size_t)b * PBLK + blockIdx.x) * CAPS + j] = stag[b][j];
    }
    for (int b = t; b < NB; b += 256)           // transposed: coalesced write
        tailcnt[blockIdx.x * NB + b] = min(scnt[b], CAPS);
}

// total[b] = ovcur[b] + sum_blk tailcnt[blk][b]; exclusive scan -> bbase
__global__ __launch_bounds__(512) void totscan_k(
    const int* __restrict__ ovcur, const int* __restrict__ tailcnt,
    int* __restrict__ bbase, int* __restrict__ rowptr_end) {
    __shared__ int sh[512];
    const int t = threadIdx.x;
    int tot = 0;
    if (t < NB) {
        for (int i = 0; i < PBLK; ++i) tot += tailcnt[i * NB + t];
        tot += ovcur[t];
    }
    sh[t] = tot;
    __syncthreads();
    for (int o = 1; o < 512; o <<= 1) {
        int x = (t >= o) ? sh[t - o] : 0;
        __syncthreads(); sh[t] += x; __syncthreads();
    }
    if (t < NB) bbase[t] = sh[t] - tot;
    if (t == NB - 1) *rowptr_end = sh[t];
}

// One block per bucket: histogram -> scan -> counting-sort in LDS -> stream out.
__global__ __launch_bounds__(256) void build_k(
    const unsigned* __restrict__ ovrecs, const int* __restrict__ ovcur,
    const unsigned* __restrict__ tailbuf, const int* __restrict__ tailcnt,
    const int* __restrict__ bbase, int* __restrict__ rowptr,
    int* __restrict__ csr, float* __restrict__ dinv, int N) {
    __shared__ int cnt[256];
    __shared__ int scan[256];
    __shared__ int lpos[256];
    __shared__ int tcs[PBLK];
    __shared__ int lcsr[CAPB];
    const int t = threadIdx.x, b = blockIdx.x;
    const int n0 = b << BSH;
    const int nn = min(256, N - n0);
    const int gbase = bbase[b];
    const size_t tb0 = (size_t)b * PBLK * CAPS;
    const int ov = ovcur[b];

    cnt[t] = 0;
    for (int i = t; i < PBLK; i += 256) tcs[i] = tailcnt[i * NB + b];
    __syncthreads();

    for (int i = t; i < PBLK * CAPS; i += 256) {
        if ((i & 31) < tcs[i >> 5]) atomicAdd(&cnt[tailbuf[tb0 + i] >> 17], 1);
    }
    for (int i = t; i < ov; i += 256) atomicAdd(&cnt[ovrecs[(size_t)b * OVCAP + i] >> 17], 1);
    __syncthreads();

    scan[t] = cnt[t];
    __syncthreads();
    for (int o = 1; o < 256; o <<= 1) {
        int x = (t >= o) ? scan[t - o] : 0;
        __syncthreads(); scan[t] += x; __syncthreads();
    }
    const int excl = scan[t] - cnt[t];
    lpos[t] = excl;
    if (t < nn) {
        rowptr[n0 + t] = gbase + excl;
        dinv[n0 + t] = rsqrtf((float)(cnt[t] + 1));  // +1 = self loop
    }
    __syncthreads();

    for (int i = t; i < PBLK * CAPS; i += 256) {
        if ((i & 31) < tcs[i >> 5]) {
            const unsigned r = tailbuf[tb0 + i];
            const int p = atomicAdd(&lpos[r >> 17], 1);
            lcsr[p] = (int)(r & 0x1FFFFu);
        }
    }
    for (int i = t; i < ov; i += 256) {
        const unsigned r = ovrecs[(size_t)b * OVCAP + i];
        const int p = atomicAdd(&lpos[r >> 17], 1);
        lcsr[p] = (int)(r & 0x1FFFFu);
    }
    __syncthreads();

    const int tot = scan[255];
    for (int i = t; i < tot; i += 256) csr[gbase + i] = lcsr[i];
}

// W12 = W1 [128x128] @ W2 [128x64] -> transposed hi/lo f16 pair (exact split);
// c2 = W2^T b1 [64] (f32).
__global__ __launch_bounds__(256) void w12_k(
    const float* __restrict__ W1, const float* __restrict__ W2,
    const float* __restrict__ b1, _Float16* __restrict__ BhiT,
    _Float16* __restrict__ BloT, float* __restrict__ c2) {
    const int t = threadIdx.x;
    if (blockIdx.x < 32) {
        const int r = blockIdx.x * 4 + (t >> 6);   // k index (input dim)
        const int c = t & 63;                      // n index (output col)
        float acc = 0.f;
        for (int k = 0; k < 128; ++k) acc += W1[r * 128 + k] * W2[k * 64 + c];
        const _Float16 h = (_Float16)acc;
        BhiT[c * 128 + r] = h;
        BloT[c * 128 + r] = (_Float16)(acc - (float)h);
    } else if (t < 64) {
        float acc = 0.f;
        for (int k = 0; k < 128; ++k) acc += b1[k] * W2[k * 64 + t];
        c2[t] = acc;
    }
}

// MFMA GEMM: g = f16( dinv * (X [N,128] @ W12 [128,64]) ).
// Block = 64 rows (4 waves x 16). Wave computes 16x64 via 4 col-tiles of
// 16x16x32 MFMA; operands split hi/lo f16 (3 products -> f32-exact).
// A-frag: m = lane&15, k = quad*8+j. B-frag: n = lane&15, k = quad*8+j.
// D: col = lane&15, row = quad*4 + reg.
__global__ __launch_bounds__(256) void gemm_mfma_k(
    const float* __restrict__ X, const _Float16* __restrict__ BhiT,
    const _Float16* __restrict__ BloT, const float* __restrict__ dinv,
    __half* __restrict__ g, int N) {
    const int t = threadIdx.x;
    const int wave = t >> 6, lane = t & 63;
    const int m16 = lane & 15;
    const int quad = lane >> 4;
    const int rowbase = blockIdx.x * 64 + wave * 16;
    const int arow = min(rowbase + m16, N - 1);   // clamp OOB reads

    floatx4 acc[4] = {{0.f,0.f,0.f,0.f},{0.f,0.f,0.f,0.f},
                      {0.f,0.f,0.f,0.f},{0.f,0.f,0.f,0.f}};

#pragma unroll
    for (int ks = 0; ks < 4; ++ks) {
        const int k0 = ks * 32 + quad * 8;
        const float4 xa = *(const float4*)(X + (size_t)arow * 128 + k0);
        const float4 xb = *(const float4*)(X + (size_t)arow * 128 + k0 + 4);
        const float xs[8] = {xa.x, xa.y, xa.z, xa.w, xb.x, xb.y, xb.z, xb.w};
        half8 ahi, alo;
#pragma unroll
        for (int j = 0; j < 8; ++j) {
            const _Float16 h = (_Float16)xs[j];
            ahi[j] = h;
            alo[j] = (_Float16)(xs[j] - (float)h);
        }
#pragma unroll
        for (int c = 0; c < 4; ++c) {
            const int n = c * 16 + m16;
            const half8 bhi = *(const half8*)(BhiT + n * 128 + k0);
            const half8 blo = *(const half8*)(BloT + n * 128 + k0);
            acc[c] = __builtin_amdgcn_mfma_f32_16x16x32_f16(ahi, bhi, acc[c], 0, 0, 0);
            acc[c] = __builtin_amdgcn_mfma_f32_16x16x32_f16(ahi, blo, acc[c], 0, 0, 0);
            acc[c] = __builtin_amdgcn_mfma_f32_16x16x32_f16(alo, bhi, acc[c], 0, 0, 0);
        }
    }

#pragma unroll
    for (int r = 0; r < 4; ++r) {
        const int grow = rowbase + quad * 4 + r;
        if (grow < N) {
            const float di = dinv[grow];
#pragma unroll
            for (int c = 0; c < 4; ++c)
                g[(size_t)grow * 64 + c * 16 + m16] = __float2half(acc[c][r] * di);
        }
    }
}

// Wave-per-node CSR gather. lanes 0-31 (slot 0) take the first half of the
// edge list, lanes 32-63 (slot 1) the second half — contiguous per slot.
// Each slot runs an 8/4/1 unroll ladder (up to 16 outstanding gathers/wave).
// lane owns features {2*pair, 2*pair+1} (pair = lane & 31); one shuffle
// combines the slot partials.
// PASS2=0: t1[d] = f16( dinv[d]^2 * (g[d] + sum g[s]) );
//          p[d]  = dinv[d] * (dinv[d] + sum dinv[s]).
// PASS2=1: out[d] = dinv[d] * (t1[d] + sum t1[s]) + p[d]*c2 + b2  (f32).
template <int PASS2>
__global__ __launch_bounds__(256) void agg_k(
    const __half* __restrict__ gin, const int* __restrict__ rowptr,
    const int* __restrict__ csr, const float* __restrict__ dinv,
    void* __restrict__ outp, float* __restrict__ p,
    const float* __restrict__ c2, const float* __restrict__ b2, int N) {
    const int d = (blockIdx.x * 256 + threadIdx.x) >> 6;
    const int lane = threadIdx.x & 63;
    if (d >= N) return;
    const int pair = lane & 31;   // half2 word within row
    const int sub  = lane >> 5;   // edge-list half
    const int beg = rowptr[d], end = rowptr[d + 1];
    const int mid = beg + ((end - beg + 1) >> 1);
    const float di = dinv[d];
    const __half2* g2 = (const __half2*)gin;

    const float2 fself = __half22float2(g2[((size_t)d << 5) + pair]);

    float accx = 0.f, accy = 0.f;
    float accp = (!PASS2 && sub == 0) ? di : 0.f;

    int e        = sub ? mid : beg;
    const int eE = sub ? end : mid;

    for (; e + 8 <= eE; e += 8) {
        int s[8];
#pragma unroll
        for (int j = 0; j < 8; ++j) s[j] = csr[e + j];
        float2 f[8];
#pragma unroll
        for (int j = 0; j < 8; ++j) f[j] = __half22float2(g2[((size_t)s[j] << 5) + pair]);
        if (!PASS2) {
#pragma unroll
            for (int j = 0; j < 8; ++j) accp += dinv[s[j]];
        }
#pragma unroll
        for (int j = 0; j < 8; ++j) { accx += f[j].x; accy += f[j].y; }
    }
    if (e + 4 <= eE) {
        int s[4];
#pragma unroll
        for (int j = 0; j < 4; ++j) s[j] = csr[e + j];
        float2 f[4];
#pragma unroll
        for (int j = 0; j < 4; ++j) f[j] = __half22float2(g2[((size_t)s[j] << 5) + pair]);
        if (!PASS2) {
#pragma unroll
            for (int j = 0; j < 4; ++j) accp += dinv[s[j]];
        }
#pragma unroll
        for (int j = 0; j < 4; ++j) { accx += f[j].x; accy += f[j].y; }
        e += 4;
    }
    for (; e < eE; ++e) {
        const int s = csr[e];
        const float2 f = __half22float2(g2[((size_t)s << 5) + pair]);
        if (!PASS2) accp += dinv[s];
        accx += f.x; accy += f.y;
    }

    // combine slot0+slot1: lanes 0-31 pull lane+32's partial
    accx += __shfl(accx, pair + 32);
    accy += __shfl(accy, pair + 32);
    if (!PASS2) accp += __shfl(accp, pair + 32);

    if (sub == 0) {
        accx += fself.x; accy += fself.y;
        if (PASS2) {
            const float2 cc = ((const float2*)c2)[pair];
            const float2 bb = ((const float2*)b2)[pair];
            const float pd = p[d];
            float2 o;
            o.x = accx * di + pd * cc.x + bb.x;
            o.y = accy * di + pd * cc.y + bb.y;
            ((float2*)outp)[((size_t)d << 5) + pair] = o;
        } else {
            const float sc = di * di;
            ((__half2*)outp)[((size_t)d << 5) + pair] =
                __floats2half2_rn(accx * sc, accy * sc);
            if (lane == 0) p[d] = di * accp;
        }
    }
}

extern "C" void kernel_launch(void* const* d_in, const int* in_sizes, int n_in,
                              void* d_out, int out_size, void* d_ws, size_t ws_size,
                              hipStream_t stream) {
    const float* x  = (const float*)d_in[0];
    const int*   ei = (const int*)d_in[1];
    const float* W1 = (const float*)d_in[2];
    const float* b1 = (const float*)d_in[3];
    const float* W2 = (const float*)d_in[4];
    const float* b2 = (const float*)d_in[5];
    float* out = (float*)d_out;

    const int N = in_sizes[0] / 128;   // 100000
    const int E = in_sizes[1] / 2;     // 3200000
    const int* src = ei;
    const int* dst = ei + E;

    char* ws = (char*)d_ws;
    auto take = [&](size_t bytes) { char* q = ws; ws += (bytes + 255) & ~(size_t)255; return q; };
    int*      ovcur   = (int*)     take(NB * 4);
    int*      bbase   = (int*)     take(NB * 4);
    int*      rowptr  = (int*)     take((size_t)(N + 1) * 4);
    float*    dinv    = (float*)   take((size_t)N * 4);
    float*    pbuf    = (float*)   take((size_t)N * 4);
    _Float16* BhiT    = (_Float16*)take(128 * 64 * 2);
    _Float16* BloT    = (_Float16*)take(128 * 64 * 2);
    float*    c2      = (float*)   take(64 * 4);
    int*      tailcnt = (int*)     take((size_t)NB * PBLK * 4);
    unsigned* ovrecs  = (unsigned*)take((size_t)NB * OVCAP * 4);
    unsigned* tailbuf = (unsigned*)take((size_t)NB * PBLK * CAPS * 4);
    int*      csr     = (int*)     take((size_t)E * 4);
    __half*   g       = (__half*)  take((size_t)N * 64 * 2);
    __half*   t1      = (__half*)  take((size_t)N * 64 * 2);

    hipMemsetAsync(ovcur, 0, NB * 4, stream);

    partition_k<<<PBLK, 256, 0, stream>>>(src, dst, ovcur, ovrecs, tailbuf, tailcnt, E);
    totscan_k<<<1, 512, 0, stream>>>(ovcur, tailcnt, bbase, rowptr + N);
    build_k<<<NB, 256, 0, stream>>>(ovrecs, ovcur, tailbuf, tailcnt, bbase, rowptr, csr, dinv, N);
    w12_k<<<33, 256, 0, stream>>>(W1, W2, b1, BhiT, BloT, c2);
    gemm_mfma_k<<<(N + 63) / 64, 256, 0, stream>>>(x, BhiT, BloT, dinv, g, N);

    const int aggBlocks = (int)(((size_t)N * 64 + 255) / 256);
    agg_k<0><<<aggBlocks, 256, 0, stream>>>(g,  rowptr, csr, dinv, t1,  pbuf, c2, b2, N);
    agg_k<1><<<aggBlocks, 256, 0, stream>>>(t1, rowptr, csr, dinv, out, pbuf, c2, b2, N);
}

// Round 10
// 344.398 us; speedup vs baseline: 9.5716x; 1.0527x over previous
//
#include <hip/hip_runtime.h>
#include <hip/hip_fp16.h>
#include <cstdint>
#include <cstddef>

// ---------------------------------------------------------------------------
// GCN 2-layer forward — linear-network restructure:
//   out = Â·(Â·(X·W12)) + p·c2ᵀ + 1·b2ᵀ,  W12 = W1·W2, c2 = W2ᵀ·b1, p = Â·1
// CSR: two-pass counting sort into FIXED per-bucket regions (no global scan).
// GEMM X·W12 via MFMA f16 exact hi/lo split. Aggregation: wave-per-node,
// lane = feature, scalarized index loads, 16-deep gather unroll.
// ---------------------------------------------------------------------------

#define NB    391     // buckets of 256 dst nodes (N = 100000 -> 391)
#define BSH   8
#define CAPS  32      // LDS stage slots per (block,bucket); Poisson(16) fits
#define PBLK  512     // partition blocks (2 per CU)
#define OVCAP 4096    // per-bucket overflow region (expected use ~0)
#define CAPB  9216    // per-bucket CSR region (mean 8184, sigma ~90; >11 sigma)

typedef _Float16 half8 __attribute__((ext_vector_type(8)));
typedef float    floatx4 __attribute__((ext_vector_type(4)));

// record: (dst & 255) << 17 | src   (src < 2^17)

__global__ __launch_bounds__(256) void partition_k(
    const int* __restrict__ src, const int* __restrict__ dst,
    int* __restrict__ ovcur, unsigned* __restrict__ ovrecs,
    unsigned* __restrict__ tailbuf, int* __restrict__ tailcnt, int E) {
    __shared__ unsigned stag[NB][CAPS + 1];   // +1 pad: spread banks
    __shared__ int scnt[NB];
    const int t = threadIdx.x;
    for (int i = t; i < NB; i += 256) scnt[i] = 0;
    __syncthreads();

    const int Q = E >> 2;                       // full int4 quads
    const int per = (Q + PBLK - 1) / PBLK;
    const int qbeg = blockIdx.x * per;
    const int qend = min(qbeg + per, Q);
    const int4* src4 = (const int4*)src;
    const int4* dst4 = (const int4*)dst;

    for (int q = qbeg + t; q < qend; q += 256) {
        const int4 s4 = src4[q];
        const int4 d4 = dst4[q];
#pragma unroll
        for (int j = 0; j < 4; ++j) {
            const int s = (&s4.x)[j], d = (&d4.x)[j];
            const int b = d >> BSH;
            const unsigned rec = ((unsigned)(d & 255) << 17) | (unsigned)s;
            const int slot = atomicAdd(&scnt[b], 1);
            if (slot < CAPS) stag[b][slot] = rec;
            else { const int p = atomicAdd(&ovcur[b], 1); ovrecs[(size_t)b * OVCAP + p] = rec; }
        }
    }
    if (blockIdx.x == 0) {                      // E % 4 remainder
        for (int e = (E & ~3) + t; e < E; e += 256) {
            const int s = src[e], d = dst[e];
            const int b = d >> BSH;
            const unsigned rec = ((unsigned)(d & 255) << 17) | (unsigned)s;
            const int slot = atomicAdd(&scnt[b], 1);
            if (slot < CAPS) stag[b][slot] = rec;
            else { const int p = atomicAdd(&ovcur[b], 1); ovrecs[(size_t)b * OVCAP + p] = rec; }
        }
    }
    __syncthreads();

    // dense dump: 32 consecutive lanes write one full 128B line per bucket
    for (int i = t; i < NB * CAPS; i += 256) {
        const int b = i >> 5, j = i & 31;
        if (j < min(scnt[b], CAPS))
            tailbuf[((size_t)b * PBLK + blockIdx.x) * CAPS + j] = stag[b][j];
    }
    for (int b = t; b < NB; b += 256)           // transposed: coalesced write
        tailcnt[blockIdx.x * NB + b] = min(scnt[b], CAPS);
}

// One block per bucket: compact tail records into LDS (single global read),
// histogram -> scan -> scatter directly into the bucket's fixed csr region.
__global__ __launch_bounds__(256) void build_k(
    const unsigned* __restrict__ ovrecs, const int* __restrict__ ovcur,
    const unsigned* __restrict__ tailbuf, const int* __restrict__ tailcnt,
    int* __restrict__ rbeg, int* __restrict__ rend,
    int* __restrict__ csr, float* __restrict__ dinv, int N) {
    __shared__ int tcs[PBLK];        // per-segment counts
    __shared__ int soff[PBLK];       // per-segment exclusive offsets
    __shared__ int sseg[256];        // pair-sum scan workspace
    __shared__ unsigned lrec[CAPB];  // compacted raw records
    __shared__ int cnt[256];
    __shared__ int scan[256];
    __shared__ int lpos[256];
    __shared__ int tcum_sh;
    const int t = threadIdx.x, b = blockIdx.x;
    const int n0 = b << BSH;
    const int nn = min(256, N - n0);
    const int gbase = b * CAPB;
    const size_t tb0 = (size_t)b * PBLK * CAPS;
    const int ov = ovcur[b];

    for (int i = t; i < PBLK; i += 256) tcs[i] = tailcnt[i * NB + b];
    cnt[t] = 0;
    __syncthreads();

    // exclusive scan over 512 segment counts (2 per thread)
    const int a0 = tcs[2 * t], a1 = tcs[2 * t + 1];
    sseg[t] = a0 + a1;
    __syncthreads();
    for (int o = 1; o < 256; o <<= 1) {
        int x = (t >= o) ? sseg[t - o] : 0;
        __syncthreads(); sseg[t] += x; __syncthreads();
    }
    const int ex2 = sseg[t] - (a0 + a1);
    soff[2 * t] = ex2;
    soff[2 * t + 1] = ex2 + a0;
    if (t == 255) tcum_sh = sseg[255];
    __syncthreads();
    const int tcum = tcum_sh;

    // compact valid tail slots + overflow into lrec (single tailbuf read)
    for (int i = t; i < PBLK * CAPS; i += 256) {
        const int seg = i >> 5, j = i & 31;
        if (j < tcs[seg]) lrec[soff[seg] + j] = tailbuf[tb0 + i];
    }
    for (int i = t; i < ov; i += 256) lrec[tcum + i] = ovrecs[(size_t)b * OVCAP + i];
    __syncthreads();

    const int tot = tcum + ov;
    for (int i = t; i < tot; i += 256) atomicAdd(&cnt[lrec[i] >> 17], 1);
    __syncthreads();

    scan[t] = cnt[t];
    __syncthreads();
    for (int o = 1; o < 256; o <<= 1) {
        int x = (t >= o) ? scan[t - o] : 0;
        __syncthreads(); scan[t] += x; __syncthreads();
    }
    const int excl = scan[t] - cnt[t];
    lpos[t] = excl;
    if (t < nn) {
        rbeg[n0 + t] = gbase + excl;
        rend[n0 + t] = gbase + scan[t];
        dinv[n0 + t] = rsqrtf((float)(cnt[t] + 1));  // +1 = self loop
    }
    __syncthreads();

    // scatter straight to the bucket's L2-local csr region
    for (int i = t; i < tot; i += 256) {
        const unsigned r = lrec[i];
        const int pq = atomicAdd(&lpos[r >> 17], 1);
        csr[gbase + pq] = (int)(r & 0x1FFFFu);
    }
}

// W12 = W1 [128x128] @ W2 [128x64] -> transposed hi/lo f16 pair (exact split);
// c2 = W2^T b1 [64] (f32).
__global__ __launch_bounds__(256) void w12_k(
    const float* __restrict__ W1, const float* __restrict__ W2,
    const float* __restrict__ b1, _Float16* __restrict__ BhiT,
    _Float16* __restrict__ BloT, float* __restrict__ c2) {
    const int t = threadIdx.x;
    if (blockIdx.x < 32) {
        const int r = blockIdx.x * 4 + (t >> 6);   // k index (input dim)
        const int c = t & 63;                      // n index (output col)
        float acc = 0.f;
        for (int k = 0; k < 128; ++k) acc += W1[r * 128 + k] * W2[k * 64 + c];
        const _Float16 h = (_Float16)acc;
        BhiT[c * 128 + r] = h;
        BloT[c * 128 + r] = (_Float16)(acc - (float)h);
    } else if (t < 64) {
        float acc = 0.f;
        for (int k = 0; k < 128; ++k) acc += b1[k] * W2[k * 64 + t];
        c2[t] = acc;
    }
}

// MFMA GEMM: g = f16( dinv * (X [N,128] @ W12 [128,64]) ).
__global__ __launch_bounds__(256) void gemm_mfma_k(
    const float* __restrict__ X, const _Float16* __restrict__ BhiT,
    const _Float16* __restrict__ BloT, const float* __restrict__ dinv,
    __half* __restrict__ g, int N) {
    const int t = threadIdx.x;
    const int wave = t >> 6, lane = t & 63;
    const int m16 = lane & 15;
    const int quad = lane >> 4;
    const int rowbase = blockIdx.x * 64 + wave * 16;
    const int arow = min(rowbase + m16, N - 1);   // clamp OOB reads

    floatx4 acc[4] = {{0.f,0.f,0.f,0.f},{0.f,0.f,0.f,0.f},
                      {0.f,0.f,0.f,0.f},{0.f,0.f,0.f,0.f}};

#pragma unroll
    for (int ks = 0; ks < 4; ++ks) {
        const int k0 = ks * 32 + quad * 8;
        const float4 xa = *(const float4*)(X + (size_t)arow * 128 + k0);
        const float4 xb = *(const float4*)(X + (size_t)arow * 128 + k0 + 4);
        const float xs[8] = {xa.x, xa.y, xa.z, xa.w, xb.x, xb.y, xb.z, xb.w};
        half8 ahi, alo;
#pragma unroll
        for (int j = 0; j < 8; ++j) {
            const _Float16 h = (_Float16)xs[j];
            ahi[j] = h;
            alo[j] = (_Float16)(xs[j] - (float)h);
        }
#pragma unroll
        for (int c = 0; c < 4; ++c) {
            const int n = c * 16 + m16;
            const half8 bhi = *(const half8*)(BhiT + n * 128 + k0);
            const half8 blo = *(const half8*)(BloT + n * 128 + k0);
            acc[c] = __builtin_amdgcn_mfma_f32_16x16x32_f16(ahi, bhi, acc[c], 0, 0, 0);
            acc[c] = __builtin_amdgcn_mfma_f32_16x16x32_f16(ahi, blo, acc[c], 0, 0, 0);
            acc[c] = __builtin_amdgcn_mfma_f32_16x16x32_f16(alo, bhi, acc[c], 0, 0, 0);
        }
    }

#pragma unroll
    for (int r = 0; r < 4; ++r) {
        const int grow = rowbase + quad * 4 + r;
        if (grow < N) {
            const float di = dinv[grow];
#pragma unroll
            for (int c = 0; c < 4; ++c)
                g[(size_t)grow * 64 + c * 16 + m16] = __float2half(acc[c][r] * di);
        }
    }
}

// Wave-per-node CSR gather, lane = feature (64 f16 feats = 128 B/row).
// d is wave-uniform (readfirstlane) so csr/dinv/row-pointer loads scalarize
// to SMEM and gathers use saddr form; 16/4/1 unroll = 16 outstanding loads.
// PASS2=0: t1[d] = f16( dinv[d]^2 * (g[d] + sum g[s]) );
//          p[d]  = dinv[d] * (dinv[d] + sum dinv[s]).
// PASS2=1: out[d] = dinv[d] * (t1[d] + sum t1[s]) + p[d]*c2 + b2  (f32).
template <int PASS2>
__global__ __launch_bounds__(256) void agg_k(
    const __half* __restrict__ gin, const int* __restrict__ rbeg,
    const int* __restrict__ rend, const int* __restrict__ csr,
    const float* __restrict__ dinv, void* __restrict__ outp,
    float* __restrict__ p, const float* __restrict__ c2,
    const float* __restrict__ b2, int N) {
    const int dd = (blockIdx.x * 256 + threadIdx.x) >> 6;
    const int d = __builtin_amdgcn_readfirstlane(dd);
    if (d >= N) return;
    const int lane = threadIdx.x & 63;
    const int beg = rbeg[d], end = rend[d];
    const float di = dinv[d];

    float acc = __half2float(gin[((size_t)d << 6) + lane]);   // self term
    float accp = PASS2 ? 0.f : di;

    int e = beg;
    for (; e + 16 <= end; e += 16) {
        int s[16];
#pragma unroll
        for (int j = 0; j < 16; ++j) s[j] = csr[e + j];
        float v[16];
#pragma unroll
        for (int j = 0; j < 16; ++j) v[j] = __half2float(gin[((size_t)s[j] << 6) + lane]);
        if (!PASS2) {
#pragma unroll
            for (int j = 0; j < 16; ++j) accp += dinv[s[j]];
        }
#pragma unroll
        for (int j = 0; j < 16; ++j) acc += v[j];
    }
    for (; e + 4 <= end; e += 4) {
        int s[4];
#pragma unroll
        for (int j = 0; j < 4; ++j) s[j] = csr[e + j];
        float v[4];
#pragma unroll
        for (int j = 0; j < 4; ++j) v[j] = __half2float(gin[((size_t)s[j] << 6) + lane]);
        if (!PASS2) {
#pragma unroll
            for (int j = 0; j < 4; ++j) accp += dinv[s[j]];
        }
#pragma unroll
        for (int j = 0; j < 4; ++j) acc += v[j];
    }
    for (; e < end; ++e) {
        const int s = csr[e];
        if (!PASS2) accp += dinv[s];
        acc += __half2float(gin[((size_t)s << 6) + lane]);
    }

    if (PASS2) {
        ((float*)outp)[((size_t)d << 6) + lane] = acc * di + p[d] * c2[lane] + b2[lane];
    } else {
        ((__half*)outp)[((size_t)d << 6) + lane] = __float2half(acc * di * di);
        if (lane == 0) p[d] = di * accp;
    }
}

extern "C" void kernel_launch(void* const* d_in, const int* in_sizes, int n_in,
                              void* d_out, int out_size, void* d_ws, size_t ws_size,
                              hipStream_t stream) {
    const float* x  = (const float*)d_in[0];
    const int*   ei = (const int*)d_in[1];
    const float* W1 = (const float*)d_in[2];
    const float* b1 = (const float*)d_in[3];
    const float* W2 = (const float*)d_in[4];
    const float* b2 = (const float*)d_in[5];
    float* out = (float*)d_out;

    const int N = in_sizes[0] / 128;   // 100000
    const int E = in_sizes[1] / 2;     // 3200000
    const int* src = ei;
    const int* dst = ei + E;

    char* ws = (char*)d_ws;
    auto take = [&](size_t bytes) { char* q = ws; ws += (bytes + 255) & ~(size_t)255; return q; };
    int*      ovcur   = (int*)     take(NB * 4);
    int*      rbeg    = (int*)     take((size_t)N * 4);
    int*      rendp   = (int*)     take((size_t)N * 4);
    float*    dinv    = (float*)   take((size_t)N * 4);
    float*    pbuf    = (float*)   take((size_t)N * 4);
    _Float16* BhiT    = (_Float16*)take(128 * 64 * 2);
    _Float16* BloT    = (_Float16*)take(128 * 64 * 2);
    float*    c2      = (float*)   take(64 * 4);
    int*      tailcnt = (int*)     take((size_t)NB * PBLK * 4);
    unsigned* ovrecs  = (unsigned*)take((size_t)NB * OVCAP * 4);
    unsigned* tailbuf = (unsigned*)take((size_t)NB * PBLK * CAPS * 4);
    int*      csr     = (int*)     take((size_t)NB * CAPB * 4);
    __half*   g       = (__half*)  take((size_t)N * 64 * 2);
    __half*   t1      = (__half*)  take((size_t)N * 64 * 2);

    hipMemsetAsync(ovcur, 0, NB * 4, stream);

    partition_k<<<PBLK, 256, 0, stream>>>(src, dst, ovcur, ovrecs, tailbuf, tailcnt, E);
    build_k<<<NB, 256, 0, stream>>>(ovrecs, ovcur, tailbuf, tailcnt, rbeg, rendp, csr, dinv, N);
    w12_k<<<33, 256, 0, stream>>>(W1, W2, b1, BhiT, BloT, c2);
    gemm_mfma_k<<<(N + 63) / 64, 256, 0, stream>>>(x, BhiT, BloT, dinv, g, N);

    const int aggBlocks = (int)(((size_t)N * 64 + 255) / 256);
    agg_k<0><<<aggBlocks, 256, 0, stream>>>(g,  rbeg, rendp, csr, dinv, t1,  pbuf, c2, b2, N);
    agg_k<1><<<aggBlocks, 256, 0, stream>>>(t1, rbeg, rendp, csr, dinv, out, pbuf, c2, b2, N);
}

// Round 11
// 328.148 us; speedup vs baseline: 10.0456x; 1.0495x over previous
//
#include <hip/hip_runtime.h>
#include <hip/hip_fp16.h>
#include <cstdint>
#include <cstddef>

// ---------------------------------------------------------------------------
// GCN 2-layer forward — linear-network restructure:
//   out = Â·(Â·(X·W12)) + p·c2ᵀ + 1·b2ᵀ,  W12 = W1·W2, c2 = W2ᵀ·b1, p = Â·1
// CSR: two-pass counting sort into FIXED per-bucket regions (no global scan).
// GEMM X·W12 via MFMA f16 exact hi/lo split. Aggregation: wave-per-node,
// two half-wave edge slots with half2 vector loads (vmcnt-pipelined; the
// round-10 scalarized variant regressed — lgkmcnt serialization).
// ---------------------------------------------------------------------------

#define NB    391     // buckets of 256 dst nodes (N = 100000 -> 391)
#define BSH   8
#define CAPS  32      // LDS stage slots per (block,bucket); Poisson(16) fits
#define PBLK  512     // partition blocks (2 per CU)
#define OVCAP 4096    // per-bucket overflow region (expected use ~0)
#define CAPB  9216    // per-bucket CSR region (mean 8184, sigma ~90; >11 sigma)

typedef _Float16 half8 __attribute__((ext_vector_type(8)));
typedef float    floatx4 __attribute__((ext_vector_type(4)));

// record: (dst & 255) << 17 | src   (src < 2^17)

__global__ __launch_bounds__(256) void partition_k(
    const int* __restrict__ src, const int* __restrict__ dst,
    int* __restrict__ ovcur, unsigned* __restrict__ ovrecs,
    unsigned* __restrict__ tailbuf, int* __restrict__ tailcnt, int E) {
    __shared__ unsigned stag[NB][CAPS + 1];   // +1 pad: spread banks
    __shared__ int scnt[NB];
    const int t = threadIdx.x;
    for (int i = t; i < NB; i += 256) scnt[i] = 0;
    __syncthreads();

    const int Q = E >> 2;                       // full int4 quads
    const int per = (Q + PBLK - 1) / PBLK;
    const int qbeg = blockIdx.x * per;
    const int qend = min(qbeg + per, Q);
    const int4* src4 = (const int4*)src;
    const int4* dst4 = (const int4*)dst;

    for (int q = qbeg + t; q < qend; q += 256) {
        const int4 s4 = src4[q];
        const int4 d4 = dst4[q];
#pragma unroll
        for (int j = 0; j < 4; ++j) {
            const int s = (&s4.x)[j], d = (&d4.x)[j];
            const int b = d >> BSH;
            const unsigned rec = ((unsigned)(d & 255) << 17) | (unsigned)s;
            const int slot = atomicAdd(&scnt[b], 1);
            if (slot < CAPS) stag[b][slot] = rec;
            else { const int p = atomicAdd(&ovcur[b], 1); ovrecs[(size_t)b * OVCAP + p] = rec; }
        }
    }
    if (blockIdx.x == 0) {                      // E % 4 remainder
        for (int e = (E & ~3) + t; e < E; e += 256) {
            const int s = src[e], d = dst[e];
            const int b = d >> BSH;
            const unsigned rec = ((unsigned)(d & 255) << 17) | (unsigned)s;
            const int slot = atomicAdd(&scnt[b], 1);
            if (slot < CAPS) stag[b][slot] = rec;
            else { const int p = atomicAdd(&ovcur[b], 1); ovrecs[(size_t)b * OVCAP + p] = rec; }
        }
    }
    __syncthreads();

    // dense dump: 32 consecutive lanes write one full 128B line per bucket
    for (int i = t; i < NB * CAPS; i += 256) {
        const int b = i >> 5, j = i & 31;
        if (j < min(scnt[b], CAPS))
            tailbuf[((size_t)b * PBLK + blockIdx.x) * CAPS + j] = stag[b][j];
    }
    for (int b = t; b < NB; b += 256)           // transposed: coalesced write
        tailcnt[blockIdx.x * NB + b] = min(scnt[b], CAPS);
}

// One block per bucket: compact tail records into LDS (single global read),
// histogram -> scan -> scatter directly into the bucket's fixed csr region.
__global__ __launch_bounds__(256) void build_k(
    const unsigned* __restrict__ ovrecs, const int* __restrict__ ovcur,
    const unsigned* __restrict__ tailbuf, const int* __restrict__ tailcnt,
    int* __restrict__ rbeg, int* __restrict__ rend,
    int* __restrict__ csr, float* __restrict__ dinv, int N) {
    __shared__ int tcs[PBLK];        // per-segment counts
    __shared__ int soff[PBLK];       // per-segment exclusive offsets
    __shared__ int sseg[256];        // pair-sum scan workspace
    __shared__ unsigned lrec[CAPB];  // compacted raw records
    __shared__ int cnt[256];
    __shared__ int scan[256];
    __shared__ int lpos[256];
    __shared__ int tcum_sh;
    const int t = threadIdx.x, b = blockIdx.x;
    const int n0 = b << BSH;
    const int nn = min(256, N - n0);
    const int gbase = b * CAPB;
    const size_t tb0 = (size_t)b * PBLK * CAPS;
    const int ov = ovcur[b];

    for (int i = t; i < PBLK; i += 256) tcs[i] = tailcnt[i * NB + b];
    cnt[t] = 0;
    __syncthreads();

    // exclusive scan over 512 segment counts (2 per thread)
    const int a0 = tcs[2 * t], a1 = tcs[2 * t + 1];
    sseg[t] = a0 + a1;
    __syncthreads();
    for (int o = 1; o < 256; o <<= 1) {
        int x = (t >= o) ? sseg[t - o] : 0;
        __syncthreads(); sseg[t] += x; __syncthreads();
    }
    const int ex2 = sseg[t] - (a0 + a1);
    soff[2 * t] = ex2;
    soff[2 * t + 1] = ex2 + a0;
    if (t == 255) tcum_sh = sseg[255];
    __syncthreads();
    const int tcum = tcum_sh;

    // compact valid tail slots + overflow into lrec (single tailbuf read)
    for (int i = t; i < PBLK * CAPS; i += 256) {
        const int seg = i >> 5, j = i & 31;
        if (j < tcs[seg]) lrec[soff[seg] + j] = tailbuf[tb0 + i];
    }
    for (int i = t; i < ov; i += 256) lrec[tcum + i] = ovrecs[(size_t)b * OVCAP + i];
    __syncthreads();

    const int tot = tcum + ov;
    for (int i = t; i < tot; i += 256) atomicAdd(&cnt[lrec[i] >> 17], 1);
    __syncthreads();

    scan[t] = cnt[t];
    __syncthreads();
    for (int o = 1; o < 256; o <<= 1) {
        int x = (t >= o) ? scan[t - o] : 0;
        __syncthreads(); scan[t] += x; __syncthreads();
    }
    const int excl = scan[t] - cnt[t];
    lpos[t] = excl;
    if (t < nn) {
        rbeg[n0 + t] = gbase + excl;
        rend[n0 + t] = gbase + scan[t];
        dinv[n0 + t] = rsqrtf((float)(cnt[t] + 1));  // +1 = self loop
    }
    __syncthreads();

    // scatter straight to the bucket's L2-local csr region
    for (int i = t; i < tot; i += 256) {
        const unsigned r = lrec[i];
        const int pq = atomicAdd(&lpos[r >> 17], 1);
        csr[gbase + pq] = (int)(r & 0x1FFFFu);
    }
}

// W12 = W1 [128x128] @ W2 [128x64] -> transposed hi/lo f16 pair (exact split);
// c2 = W2^T b1 [64] (f32).
__global__ __launch_bounds__(256) void w12_k(
    const float* __restrict__ W1, const float* __restrict__ W2,
    const float* __restrict__ b1, _Float16* __restrict__ BhiT,
    _Float16* __restrict__ BloT, float* __restrict__ c2) {
    const int t = threadIdx.x;
    if (blockIdx.x < 32) {
        const int r = blockIdx.x * 4 + (t >> 6);   // k index (input dim)
        const int c = t & 63;                      // n index (output col)
        float acc = 0.f;
        for (int k = 0; k < 128; ++k) acc += W1[r * 128 + k] * W2[k * 64 + c];
        const _Float16 h = (_Float16)acc;
        BhiT[c * 128 + r] = h;
        BloT[c * 128 + r] = (_Float16)(acc - (float)h);
    } else if (t < 64) {
        float acc = 0.f;
        for (int k = 0; k < 128; ++k) acc += b1[k] * W2[k * 64 + t];
        c2[t] = acc;
    }
}

// MFMA GEMM: g = f16( dinv * (X [N,128] @ W12 [128,64]) ).
__global__ __launch_bounds__(256) void gemm_mfma_k(
    const float* __restrict__ X, const _Float16* __restrict__ BhiT,
    const _Float16* __restrict__ BloT, const float* __restrict__ dinv,
    __half* __restrict__ g, int N) {
    const int t = threadIdx.x;
    const int wave = t >> 6, lane = t & 63;
    const int m16 = lane & 15;
    const int quad = lane >> 4;
    const int rowbase = blockIdx.x * 64 + wave * 16;
    const int arow = min(rowbase + m16, N - 1);   // clamp OOB reads

    floatx4 acc[4] = {{0.f,0.f,0.f,0.f},{0.f,0.f,0.f,0.f},
                      {0.f,0.f,0.f,0.f},{0.f,0.f,0.f,0.f}};

#pragma unroll
    for (int ks = 0; ks < 4; ++ks) {
        const int k0 = ks * 32 + quad * 8;
        const float4 xa = *(const float4*)(X + (size_t)arow * 128 + k0);
        const float4 xb = *(const float4*)(X + (size_t)arow * 128 + k0 + 4);
        const float xs[8] = {xa.x, xa.y, xa.z, xa.w, xb.x, xb.y, xb.z, xb.w};
        half8 ahi, alo;
#pragma unroll
        for (int j = 0; j < 8; ++j) {
            const _Float16 h = (_Float16)xs[j];
            ahi[j] = h;
            alo[j] = (_Float16)(xs[j] - (float)h);
        }
#pragma unroll
        for (int c = 0; c < 4; ++c) {
            const int n = c * 16 + m16;
            const half8 bhi = *(const half8*)(BhiT + n * 128 + k0);
            const half8 blo = *(const half8*)(BloT + n * 128 + k0);
            acc[c] = __builtin_amdgcn_mfma_f32_16x16x32_f16(ahi, bhi, acc[c], 0, 0, 0);
            acc[c] = __builtin_amdgcn_mfma_f32_16x16x32_f16(ahi, blo, acc[c], 0, 0, 0);
            acc[c] = __builtin_amdgcn_mfma_f32_16x16x32_f16(alo, bhi, acc[c], 0, 0, 0);
        }
    }

#pragma unroll
    for (int r = 0; r < 4; ++r) {
        const int grow = rowbase + quad * 4 + r;
        if (grow < N) {
            const float di = dinv[grow];
#pragma unroll
            for (int c = 0; c < 4; ++c)
                g[(size_t)grow * 64 + c * 16 + m16] = __float2half(acc[c][r] * di);
        }
    }
}

// Wave-per-node CSR gather. lanes 0-31 (slot 0) take the first half of the
// edge list, lanes 32-63 (slot 1) the second half — contiguous per slot.
// Each slot runs an 8/4/1 unroll ladder (up to 16 outstanding gathers/wave).
// lane owns features {2*pair, 2*pair+1} (pair = lane & 31); one shuffle
// combines the slot partials. (Vector index loads — vmcnt-pipelined.)
// PASS2=0: t1[d] = f16( dinv[d]^2 * (g[d] + sum g[s]) );
//          p[d]  = dinv[d] * (dinv[d] + sum dinv[s]).
// PASS2=1: out[d] = dinv[d] * (t1[d] + sum t1[s]) + p[d]*c2 + b2  (f32).
template <int PASS2>
__global__ __launch_bounds__(256) void agg_k(
    const __half* __restrict__ gin, const int* __restrict__ rbeg,
    const int* __restrict__ rend, const int* __restrict__ csr,
    const float* __restrict__ dinv, void* __restrict__ outp,
    float* __restrict__ p, const float* __restrict__ c2,
    const float* __restrict__ b2, int N) {
    const int d = (blockIdx.x * 256 + threadIdx.x) >> 6;
    const int lane = threadIdx.x & 63;
    if (d >= N) return;
    const int pair = lane & 31;   // half2 word within row
    const int sub  = lane >> 5;   // edge-list half
    const int beg = rbeg[d], end = rend[d];
    const int mid = beg + ((end - beg + 1) >> 1);
    const float di = dinv[d];
    const __half2* g2 = (const __half2*)gin;

    const float2 fself = __half22float2(g2[((size_t)d << 5) + pair]);

    float accx = 0.f, accy = 0.f;
    float accp = (!PASS2 && sub == 0) ? di : 0.f;

    int e        = sub ? mid : beg;
    const int eE = sub ? end : mid;

    for (; e + 8 <= eE; e += 8) {
        int s[8];
#pragma unroll
        for (int j = 0; j < 8; ++j) s[j] = csr[e + j];
        float2 f[8];
#pragma unroll
        for (int j = 0; j < 8; ++j) f[j] = __half22float2(g2[((size_t)s[j] << 5) + pair]);
        if (!PASS2) {
#pragma unroll
            for (int j = 0; j < 8; ++j) accp += dinv[s[j]];
        }
#pragma unroll
        for (int j = 0; j < 8; ++j) { accx += f[j].x; accy += f[j].y; }
    }
    if (e + 4 <= eE) {
        int s[4];
#pragma unroll
        for (int j = 0; j < 4; ++j) s[j] = csr[e + j];
        float2 f[4];
#pragma unroll
        for (int j = 0; j < 4; ++j) f[j] = __half22float2(g2[((size_t)s[j] << 5) + pair]);
        if (!PASS2) {
#pragma unroll
            for (int j = 0; j < 4; ++j) accp += dinv[s[j]];
        }
#pragma unroll
        for (int j = 0; j < 4; ++j) { accx += f[j].x; accy += f[j].y; }
        e += 4;
    }
    for (; e < eE; ++e) {
        const int s = csr[e];
        const float2 f = __half22float2(g2[((size_t)s << 5) + pair]);
        if (!PASS2) accp += dinv[s];
        accx += f.x; accy += f.y;
    }

    // combine slot0+slot1: lanes 0-31 pull lane+32's partial
    accx += __shfl(accx, pair + 32);
    accy += __shfl(accy, pair + 32);
    if (!PASS2) accp += __shfl(accp, pair + 32);

    if (sub == 0) {
        accx += fself.x; accy += fself.y;
        if (PASS2) {
            const float2 cc = ((const float2*)c2)[pair];
            const float2 bb = ((const float2*)b2)[pair];
            const float pd = p[d];
            float2 o;
            o.x = accx * di + pd * cc.x + bb.x;
            o.y = accy * di + pd * cc.y + bb.y;
            ((float2*)outp)[((size_t)d << 5) + pair] = o;
        } else {
            const float sc = di * di;
            ((__half2*)outp)[((size_t)d << 5) + pair] =
                __floats2half2_rn(accx * sc, accy * sc);
            if (lane == 0) p[d] = di * accp;
        }
    }
}

extern "C" void kernel_launch(void* const* d_in, const int* in_sizes, int n_in,
                              void* d_out, int out_size, void* d_ws, size_t ws_size,
                              hipStream_t stream) {
    const float* x  = (const float*)d_in[0];
    const int*   ei = (const int*)d_in[1];
    const float* W1 = (const float*)d_in[2];
    const float* b1 = (const float*)d_in[3];
    const float* W2 = (const float*)d_in[4];
    const float* b2 = (const float*)d_in[5];
    float* out = (float*)d_out;

    const int N = in_sizes[0] / 128;   // 100000
    const int E = in_sizes[1] / 2;     // 3200000
    const int* src = ei;
    const int* dst = ei + E;

    char* ws = (char*)d_ws;
    auto take = [&](size_t bytes) { char* q = ws; ws += (bytes + 255) & ~(size_t)255; return q; };
    int*      ovcur   = (int*)     take(NB * 4);
    int*      rbeg    = (int*)     take((size_t)N * 4);
    int*      rendp   = (int*)     take((size_t)N * 4);
    float*    dinv    = (float*)   take((size_t)N * 4);
    float*    pbuf    = (float*)   take((size_t)N * 4);
    _Float16* BhiT    = (_Float16*)take(128 * 64 * 2);
    _Float16* BloT    = (_Float16*)take(128 * 64 * 2);
    float*    c2      = (float*)   take(64 * 4);
    int*      tailcnt = (int*)     take((size_t)NB * PBLK * 4);
    unsigned* ovrecs  = (unsigned*)take((size_t)NB * OVCAP * 4);
    unsigned* tailbuf = (unsigned*)take((size_t)NB * PBLK * CAPS * 4);
    int*      csr     = (int*)     take((size_t)NB * CAPB * 4);
    __half*   g       = (__half*)  take((size_t)N * 64 * 2);
    __half*   t1      = (__half*)  take((size_t)N * 64 * 2);

    hipMemsetAsync(ovcur, 0, NB * 4, stream);

    partition_k<<<PBLK, 256, 0, stream>>>(src, dst, ovcur, ovrecs, tailbuf, tailcnt, E);
    build_k<<<NB, 256, 0, stream>>>(ovrecs, ovcur, tailbuf, tailcnt, rbeg, rendp, csr, dinv, N);
    w12_k<<<33, 256, 0, stream>>>(W1, W2, b1, BhiT, BloT, c2);
    gemm_mfma_k<<<(N + 63) / 64, 256, 0, stream>>>(x, BhiT, BloT, dinv, g, N);

    const int aggBlocks = (int)(((size_t)N * 64 + 255) / 256);
    agg_k<0><<<aggBlocks, 256, 0, stream>>>(g,  rbeg, rendp, csr, dinv, t1,  pbuf, c2, b2, N);
    agg_k<1><<<aggBlocks, 256, 0, stream>>>(t1, rbeg, rendp, csr, dinv, out, pbuf, c2, b2, N);
}